// Round 10
// baseline (326.230 us; speedup 1.0000x reference)
//
#include <hip/hip_runtime.h>
#include <hip/hip_bf16.h>
#include <cfloat>

#define NTOK 4096
#define D_ 1024
#define DICT_ 16384
#define TOPK 8
#define NCAND 12
#define LN_EPS 1e-5f

typedef __attribute__((ext_vector_type(8))) short bf16x8;
typedef __attribute__((ext_vector_type(4))) float f32x4;
typedef __attribute__((ext_vector_type(8))) unsigned short us8;
typedef __attribute__((ext_vector_type(4))) unsigned short us4;

__device__ __forceinline__ unsigned short f2bf(float f) {
    unsigned int u = __float_as_uint(f);
    u += 0x7fffu + ((u >> 16) & 1u);   // RNE
    return (unsigned short)(u >> 16);
}
__device__ __forceinline__ float bf2f(unsigned short u) {
    return __uint_as_float(((unsigned int)u) << 16);
}

__device__ __forceinline__ void gl2lds16(const void* gsrc, void* ldsdst) {
    __builtin_amdgcn_global_load_lds(
        (const __attribute__((address_space(1))) unsigned int*)gsrc,
        (__attribute__((address_space(3))) unsigned int*)ldsdst, 16, 0, 0);
}

// ---------------- K1: LayerNorm -> bf16 normed ----------------
__global__ __launch_bounds__(256) void ln_kernel(const float* __restrict__ x,
                                                 const float* __restrict__ gamma,
                                                 const float* __restrict__ beta,
                                                 unsigned short* __restrict__ nb) {
    int t = blockIdx.x;
    int tid = threadIdx.x;
    const float4 v = ((const float4*)(x + (size_t)t * D_))[tid];

    float s = v.x + v.y + v.z + v.w;
    #pragma unroll
    for (int off = 32; off > 0; off >>= 1) s += __shfl_down(s, off, 64);
    __shared__ float red[4];
    int wid = tid >> 6, lane = tid & 63;
    if (lane == 0) red[wid] = s;
    __syncthreads();
    float mu = (red[0] + red[1] + red[2] + red[3]) * (1.0f / D_);
    __syncthreads();

    float dx = v.x - mu, dy = v.y - mu, dz = v.z - mu, dw = v.w - mu;
    float ss = dx * dx + dy * dy + dz * dz + dw * dw;
    #pragma unroll
    for (int off = 32; off > 0; off >>= 1) ss += __shfl_down(ss, off, 64);
    if (lane == 0) red[wid] = ss;
    __syncthreads();
    float var = (red[0] + red[1] + red[2] + red[3]) * (1.0f / D_);
    float rs = rsqrtf(var + LN_EPS);

    const float4 g = ((const float4*)gamma)[tid];
    const float4 b = ((const float4*)beta)[tid];
    us4 o;
    o.x = f2bf(dx * rs * g.x + b.x);
    o.y = f2bf(dy * rs * g.y + b.y);
    o.z = f2bf(dz * rs * g.z + b.z);
    o.w = f2bf(dw * rs * g.w + b.w);
    ((us4*)(nb + (size_t)t * D_))[tid] = o;
}

// ---------------- K1b: W_enc fp32 -> bf16 ----------------
__global__ __launch_bounds__(256) void cvt_kernel(const float* __restrict__ W,
                                                  unsigned short* __restrict__ Wb) {
    const int tid = threadIdx.x;
    const size_t base = (size_t)blockIdx.x * 1024;
    #pragma unroll
    for (int j = 0; j < 4; j++) {
        size_t i = base + j * 256 + tid;
        float4 f = ((const float4*)W)[i];
        us4 o;
        o.x = f2bf(f.x); o.y = f2bf(f.y); o.z = f2bf(f.z); o.w = f2bf(f.w);
        ((us4*)Wb)[i] = o;
    }
}

// ---------------- K2: 256x256 bf16 MFMA GEMM, 4-phase/K-tile counted-vmcnt ----------------
// 512 threads = 8 waves (2M x 4N). Wave tile 128x64 (8x4 16x16 frags). BK=64.
// LDS: 2 buffers x (A 256x64 + B 256x64) bf16 = 128 KiB, 3-bit XOR swizzle.
// Each K-tile: 4 phases of 16 MFMA, each in its own barrier pair with
// lgkmcnt(0)+sched_barrier (rule #18) and setprio(T5); one counted vmcnt(4)
// (T4: next-tile A loads stay in flight). XCD-swizzled blockIdx (T1).
__global__ __launch_bounds__(512, 1) void gemm_kernel(const unsigned short* __restrict__ A,
                                                      const unsigned short* __restrict__ B,
                                                      unsigned short* __restrict__ L) {
    __shared__ unsigned short lds[2][2][256][64];
    const int tid = threadIdx.x;
    const int lane = tid & 63;
    const int w = tid >> 6;
    const int wm = w >> 2, wn = w & 3;

    // XCD-aware swizzle: nwg=1024=8*128, XCD x gets logical tiles with
    // col-blocks 8x..8x+7 over all 16 row-blocks (B panels L2-resident per XCD)
    const int lin = blockIdx.x;
    const int swz = (lin & 7) * 128 + (lin >> 3);
    const int col0 = (swz >> 4) * 256;   // dict cols (64 col-blocks)
    const int row0 = (swz & 15) * 256;   // token rows (16 row-blocks)

    f32x4 acc[8][4] = {};

    auto stage = [&](int b, int mat, const unsigned short* __restrict__ G,
                     int rbase, int k0, int h) {
        unsigned short* plane = &lds[b][mat][0][0];
        #pragma unroll
        for (int i = 0; i < 2; i++) {
            const int cb = h * 1024 + i * 512 + w * 64;   // wave-uniform chunk base
            const int c = cb + lane;
            const int r = c >> 3, sl = c & 7, g = sl ^ (r & 7);
            gl2lds16(G + (size_t)(rbase + r) * 1024 + k0 + g * 8, plane + (size_t)cb * 8);
        }
    };

    // prologue: stage tile 0 into buf 0 (8 loads/thread outstanding)
    stage(0, 0, A, row0, 0, 0);
    stage(0, 0, A, row0, 0, 1);
    stage(0, 1, B, col0, 0, 0);
    stage(0, 1, B, col0, 0, 1);

    const int arow = wm * 128 + (lane & 15);
    const int brow = wn * 64 + (lane & 15);
    const int kg = lane >> 4;

    bf16x8 afA[4], afB[4], b4[4];

    for (int t = 0; t < 16; t++) {
        const int cur = t & 1, nxt = cur ^ 1;
        const int kn = ((t + 1) & 15) * 64;   // wrap-around keeps loop uniform

        // ======== phase 0: stage next A; vmcnt(4); read m0-3/kk0 + B/kk0; MFMA m0-3 x n0-3 kk0
        stage(nxt, 0, A, row0, kn, 0);
        stage(nxt, 0, A, row0, kn, 1);
        asm volatile("s_waitcnt vmcnt(4)" ::: "memory");
        __builtin_amdgcn_s_barrier();
        __builtin_amdgcn_sched_barrier(0);

        #pragma unroll
        for (int m = 0; m < 4; m++) {
            const int r = arow + m * 16;
            afA[m] = *(const bf16x8*)&lds[cur][0][r][(kg ^ (r & 7)) * 8];
        }
        #pragma unroll
        for (int n = 0; n < 4; n++) {
            const int r = brow + n * 16;
            b4[n] = *(const bf16x8*)&lds[cur][1][r][(kg ^ (r & 7)) * 8];
        }
        asm volatile("s_waitcnt lgkmcnt(0)" ::: "memory");
        __builtin_amdgcn_sched_barrier(0);
        __builtin_amdgcn_s_setprio(1);
        #pragma unroll
        for (int m = 0; m < 4; m++)
            #pragma unroll
            for (int n = 0; n < 4; n++)
                acc[m][n] = __builtin_amdgcn_mfma_f32_16x16x32_bf16(afA[m], b4[n], acc[m][n], 0, 0, 0);
        __builtin_amdgcn_s_setprio(0);
        __builtin_amdgcn_s_barrier();
        asm volatile("" ::: "memory");

        // ======== phase 1: read m4-7/kk0; stage next B h0; MFMA m4-7 x n0-3 kk0
        #pragma unroll
        for (int m = 0; m < 4; m++) {
            const int r = arow + 64 + m * 16;
            afB[m] = *(const bf16x8*)&lds[cur][0][r][(kg ^ (r & 7)) * 8];
        }
        stage(nxt, 1, B, col0, kn, 0);
        __builtin_amdgcn_s_barrier();
        asm volatile("s_waitcnt lgkmcnt(0)" ::: "memory");
        __builtin_amdgcn_sched_barrier(0);
        __builtin_amdgcn_s_setprio(1);
        #pragma unroll
        for (int m = 0; m < 4; m++)
            #pragma unroll
            for (int n = 0; n < 4; n++)
                acc[4 + m][n] = __builtin_amdgcn_mfma_f32_16x16x32_bf16(afB[m], b4[n], acc[4 + m][n], 0, 0, 0);
        __builtin_amdgcn_s_setprio(0);
        __builtin_amdgcn_s_barrier();
        asm volatile("" ::: "memory");

        // ======== phase 2: read m0-3/kk1 + B/kk1; stage next B h1; MFMA m0-3 x n0-3 kk1
        #pragma unroll
        for (int m = 0; m < 4; m++) {
            const int r = arow + m * 16;
            afA[m] = *(const bf16x8*)&lds[cur][0][r][((4 + kg) ^ (r & 7)) * 8];
        }
        #pragma unroll
        for (int n = 0; n < 4; n++) {
            const int r = brow + n * 16;
            b4[n] = *(const bf16x8*)&lds[cur][1][r][((4 + kg) ^ (r & 7)) * 8];
        }
        stage(nxt, 1, B, col0, kn, 1);
        __builtin_amdgcn_s_barrier();
        asm volatile("s_waitcnt lgkmcnt(0)" ::: "memory");
        __builtin_amdgcn_sched_barrier(0);
        __builtin_amdgcn_s_setprio(1);
        #pragma unroll
        for (int m = 0; m < 4; m++)
            #pragma unroll
            for (int n = 0; n < 4; n++)
                acc[m][n] = __builtin_amdgcn_mfma_f32_16x16x32_bf16(afA[m], b4[n], acc[m][n], 0, 0, 0);
        __builtin_amdgcn_s_setprio(0);
        __builtin_amdgcn_s_barrier();
        asm volatile("" ::: "memory");

        // ======== phase 3: read m4-7/kk1; MFMA m4-7 x n0-3 kk1
        #pragma unroll
        for (int m = 0; m < 4; m++) {
            const int r = arow + 64 + m * 16;
            afB[m] = *(const bf16x8*)&lds[cur][0][r][((4 + kg) ^ (r & 7)) * 8];
        }
        __builtin_amdgcn_s_barrier();
        asm volatile("s_waitcnt lgkmcnt(0)" ::: "memory");
        __builtin_amdgcn_sched_barrier(0);
        __builtin_amdgcn_s_setprio(1);
        #pragma unroll
        for (int m = 0; m < 4; m++)
            #pragma unroll
            for (int n = 0; n < 4; n++)
                acc[4 + m][n] = __builtin_amdgcn_mfma_f32_16x16x32_bf16(afB[m], b4[n], acc[4 + m][n], 0, 0, 0);
        __builtin_amdgcn_s_setprio(0);
        __builtin_amdgcn_s_barrier();
        asm volatile("" ::: "memory");
    }

    // epilogue: C/D layout col=lane&15, row=(lane>>4)*4+reg
    #pragma unroll
    for (int m = 0; m < 8; m++) {
        const int rb = row0 + wm * 128 + m * 16 + (lane >> 4) * 4;
        #pragma unroll
        for (int n = 0; n < 4; n++) {
            const int col = col0 + wn * 64 + n * 16 + (lane & 15);
            #pragma unroll
            for (int r = 0; r < 4; r++)
                L[(size_t)(rb + r) * DICT_ + col] = f2bf(acc[m][n][r]);
        }
    }
}

// ---------------- K3: per-token top-12 candidates from bf16 logits ----------------
__global__ __launch_bounds__(256) void cand_kernel(const unsigned short* __restrict__ L,
                                                   int* __restrict__ cand) {
    const int token = blockIdx.x;
    const int tid = threadIdx.x;
    const unsigned short* row = L + (size_t)token * DICT_;

    float v[5];
    int id[5];
    #pragma unroll
    for (int j = 0; j < 5; j++) { v[j] = -FLT_MAX; id[j] = -1; }

    for (int j = 0; j < 8; j++) {
        const int fi = j * 256 + tid;            // 16B group index (2048 per row)
        const us8 u = *(const us8*)&row[fi * 8];
        #pragma unroll
        for (int e = 0; e < 8; e++) {
            const float f = bf2f(u[e]);
            if (f > v[4]) {
                v[4] = f; id[4] = fi * 8 + e;
                #pragma unroll
                for (int q = 4; q > 0; q--) {
                    if (v[q] > v[q - 1]) {
                        float tv = v[q]; v[q] = v[q - 1]; v[q - 1] = tv;
                        int ti = id[q]; id[q] = id[q - 1]; id[q - 1] = ti;
                    }
                }
            }
        }
    }

    __shared__ float hv[256];
    __shared__ int hi[256];
    __shared__ int hp[256];
    __shared__ int wt;
    hv[tid] = v[0];
    hi[tid] = id[0];
    hp[tid] = 0;

    for (int round = 0; round < NCAND; round++) {
        __syncthreads();
        if (tid < 64) {
            float bv = hv[tid]; int bt = tid;
            #pragma unroll
            for (int q = 1; q < 4; q++) {
                const int t2 = tid + q * 64;
                const float v2 = hv[t2];
                if (v2 > bv || (v2 == bv && t2 < bt)) { bv = v2; bt = t2; }
            }
            #pragma unroll
            for (int off = 32; off > 0; off >>= 1) {
                const float ov = __shfl_down(bv, off, 64);
                const int ot = __shfl_down(bt, off, 64);
                if (ov > bv || (ov == bv && ot < bt)) { bv = ov; bt = ot; }
            }
            if (tid == 0) wt = bt;
        }
        __syncthreads();
        if (tid == wt) {
            cand[(size_t)token * NCAND + round] = hi[tid];
            const int p = hp[tid] + 1;
            hp[tid] = p;
            if (p < 5) { hv[tid] = v[p]; hi[tid] = id[p]; }
            else { hv[tid] = -FLT_MAX; hi[tid] = -1; }
        }
    }
}

// ---------------- K4: exact fp32 refine of 12 candidates -> top-8 sel ----------------
__global__ __launch_bounds__(256) void refine_kernel(const float* __restrict__ x,
                                                     const float* __restrict__ gamma,
                                                     const float* __restrict__ beta,
                                                     const float* __restrict__ Wenc,
                                                     const int* __restrict__ cand,
                                                     float* __restrict__ sel_val,
                                                     int* __restrict__ sel_idx) {
    const int token = blockIdx.x;
    const int tid = threadIdx.x;
    const int lane = tid & 63;
    const int w = tid >> 6;

    __shared__ float red[4];
    __shared__ float ln[D_];

    const float4 v = ((const float4*)(x + (size_t)token * D_))[tid];
    float s = v.x + v.y + v.z + v.w;
    #pragma unroll
    for (int off = 32; off > 0; off >>= 1) s += __shfl_down(s, off, 64);
    if (lane == 0) red[w] = s;
    __syncthreads();
    float mu = (red[0] + red[1] + red[2] + red[3]) * (1.0f / D_);
    __syncthreads();
    float dx = v.x - mu, dy = v.y - mu, dz = v.z - mu, dw = v.w - mu;
    float ss = dx * dx + dy * dy + dz * dz + dw * dw;
    #pragma unroll
    for (int off = 32; off > 0; off >>= 1) ss += __shfl_down(ss, off, 64);
    if (lane == 0) red[w] = ss;
    __syncthreads();
    float var = (red[0] + red[1] + red[2] + red[3]) * (1.0f / D_);
    float rs = rsqrtf(var + LN_EPS);
    const float4 g = ((const float4*)gamma)[tid];
    const float4 b = ((const float4*)beta)[tid];
    float4 o;
    o.x = dx * rs * g.x + b.x;
    o.y = dy * rs * g.y + b.y;
    o.z = dz * rs * g.z + b.z;
    o.w = dw * rs * g.w + b.w;
    ((float4*)ln)[tid] = o;
    __syncthreads();

    __shared__ float dv[NCAND];
    __shared__ int di_s[NCAND];
    for (int c = w; c < NCAND; c += 4) {
        const int di = cand[(size_t)token * NCAND + c];
        const float4* wr = (const float4*)(Wenc + (size_t)di * D_);
        float acc = 0.f;
        #pragma unroll
        for (int j = 0; j < 4; j++) {
            const float4 q = wr[j * 64 + lane];
            const float4 p = ((const float4*)ln)[j * 64 + lane];
            acc += q.x * p.x + q.y * p.y + q.z * p.z + q.w * p.w;
        }
        #pragma unroll
        for (int off = 32; off > 0; off >>= 1) acc += __shfl_down(acc, off, 64);
        if (lane == 0) { dv[c] = acc; di_s[c] = di; }
    }
    __syncthreads();

    __shared__ float wv[TOPK];
    __shared__ int wi[TOPK];
    if (tid == 0) {
        unsigned int used = 0;
        for (int p = 0; p < TOPK; p++) {
            float bv = -FLT_MAX; int bc = -1;
            for (int c = 0; c < NCAND; c++) {
                if (used & (1u << c)) continue;
                const float cv = dv[c];
                if (cv > bv || (cv == bv && di_s[c] < ((bc >= 0) ? di_s[bc] : 0x7fffffff))) { bv = cv; bc = c; }
            }
            used |= 1u << bc;
            wv[p] = dv[bc]; wi[p] = di_s[bc];
        }
    }
    __syncthreads();
    if (tid < TOPK) {
        sel_val[(size_t)token * TOPK + tid] = wv[tid];
        sel_idx[(size_t)token * TOPK + tid] = wi[tid];
    }
}

// ---------------- K5: fused sparse-row writer + reconstruction ----------------
__global__ __launch_bounds__(256) void sparse_recon_kernel(const float* __restrict__ sel_val,
                                                           const int* __restrict__ sel_idx,
                                                           const float* __restrict__ Wdict,
                                                           float* __restrict__ sparse,
                                                           float* __restrict__ recon) {
    const int token = blockIdx.x;
    const int tid = threadIdx.x;
    __shared__ float v8[TOPK];
    __shared__ int i8[TOPK];
    if (tid < TOPK) {
        v8[tid] = sel_val[(size_t)token * TOPK + tid];
        i8[tid] = sel_idx[(size_t)token * TOPK + tid];
    }
    __syncthreads();

    // issue recon loads early (latency hides under the store stream)
    float4 wr[TOPK];
    #pragma unroll
    for (int j = 0; j < TOPK; j++)
        wr[j] = ((const float4*)(Wdict + (size_t)i8[j] * D_))[tid];

    f32x4* row = (f32x4*)(sparse + (size_t)token * DICT_);
    #pragma unroll
    for (int q = 0; q < 16; q++) {
        const int grp = q * 256 + tid;       // 4096 groups: full row
        const int base = grp * 4;
        f32x4 o = {0.f, 0.f, 0.f, 0.f};
        #pragma unroll
        for (int j = 0; j < TOPK; j++) {
            const int rel = i8[j] - base;
            o.x = (rel == 0) ? v8[j] : o.x;
            o.y = (rel == 1) ? v8[j] : o.y;
            o.z = (rel == 2) ? v8[j] : o.z;
            o.w = (rel == 3) ? v8[j] : o.w;
        }
        __builtin_nontemporal_store(o, row + grp);
    }

    float4 acc = {0.f, 0.f, 0.f, 0.f};
    #pragma unroll
    for (int j = 0; j < TOPK; j++) {
        const float c = v8[j];
        acc.x = fmaf(c, wr[j].x, acc.x);
        acc.y = fmaf(c, wr[j].y, acc.y);
        acc.z = fmaf(c, wr[j].z, acc.z);
        acc.w = fmaf(c, wr[j].w, acc.w);
    }
    ((float4*)(recon + (size_t)token * D_))[tid] = acc;
}

extern "C" void kernel_launch(void* const* d_in, const int* in_sizes, int n_in,
                              void* d_out, int out_size, void* d_ws, size_t ws_size,
                              hipStream_t stream) {
    const float* x = (const float*)d_in[0];
    const float* gamma = (const float*)d_in[1];
    const float* beta = (const float*)d_in[2];
    const float* Wenc = (const float*)d_in[3];
    const float* Wdict = (const float*)d_in[4];

    float* recon = (float*)d_out;
    float* sparse = (float*)d_out + (size_t)NTOK * D_;

    // all scratch in d_ws (~176.5 MB)
    unsigned short* Lg = (unsigned short*)d_ws;                   // bf16 logits, 134 MB
    unsigned short* We = Lg + (size_t)NTOK * DICT_;               // bf16 W_enc, 33.5 MB
    unsigned short* Nb = We + (size_t)DICT_ * D_;                 // bf16 normed, 8 MB
    int* cand = (int*)(Nb + (size_t)NTOK * D_);                   // 4096*12 int
    float* sel_val = (float*)(cand + (size_t)NTOK * NCAND);       // 4096*8 f32
    int* sel_idx = (int*)(sel_val + (size_t)NTOK * TOPK);         // 4096*8 int

    ln_kernel<<<NTOK, 256, 0, stream>>>(x, gamma, beta, Nb);
    cvt_kernel<<<DICT_ * D_ / 4096, 256, 0, stream>>>(Wenc, We);

    gemm_kernel<<<(DICT_ / 256) * (NTOK / 256), 512, 0, stream>>>(Nb, We, Lg);

    cand_kernel<<<NTOK, 256, 0, stream>>>(Lg, cand);

    refine_kernel<<<NTOK, 256, 0, stream>>>(x, gamma, beta, Wenc, cand,
                                            sel_val, sel_idx);

    sparse_recon_kernel<<<NTOK, 256, 0, stream>>>(sel_val, sel_idx, Wdict,
                                                  sparse, recon);
}

// Round 11
// 324.011 us; speedup vs baseline: 1.0069x; 1.0069x over previous
//
#include <hip/hip_runtime.h>
#include <hip/hip_bf16.h>
#include <cfloat>

#define NTOK 4096
#define D_ 1024
#define DICT_ 16384
#define TOPK 8
#define NCAND 12
#define LN_EPS 1e-5f

typedef __attribute__((ext_vector_type(8))) short bf16x8;
typedef __attribute__((ext_vector_type(4))) float f32x4;
typedef __attribute__((ext_vector_type(8))) unsigned short us8;
typedef __attribute__((ext_vector_type(4))) unsigned short us4;

__device__ __forceinline__ unsigned short f2bf(float f) {
    unsigned int u = __float_as_uint(f);
    u += 0x7fffu + ((u >> 16) & 1u);   // RNE
    return (unsigned short)(u >> 16);
}
__device__ __forceinline__ float bf2f(unsigned short u) {
    return __uint_as_float(((unsigned int)u) << 16);
}

__device__ __forceinline__ void gl2lds16(const void* gsrc, void* ldsdst) {
    __builtin_amdgcn_global_load_lds(
        (const __attribute__((address_space(1))) unsigned int*)gsrc,
        (__attribute__((address_space(3))) unsigned int*)ldsdst, 16, 0, 0);
}

// ---------------- K1: LayerNorm -> bf16 normed ----------------
__global__ __launch_bounds__(256) void ln_kernel(const float* __restrict__ x,
                                                 const float* __restrict__ gamma,
                                                 const float* __restrict__ beta,
                                                 unsigned short* __restrict__ nb) {
    int t = blockIdx.x;
    int tid = threadIdx.x;
    const float4 v = ((const float4*)(x + (size_t)t * D_))[tid];

    float s = v.x + v.y + v.z + v.w;
    #pragma unroll
    for (int off = 32; off > 0; off >>= 1) s += __shfl_down(s, off, 64);
    __shared__ float red[4];
    int wid = tid >> 6, lane = tid & 63;
    if (lane == 0) red[wid] = s;
    __syncthreads();
    float mu = (red[0] + red[1] + red[2] + red[3]) * (1.0f / D_);
    __syncthreads();

    float dx = v.x - mu, dy = v.y - mu, dz = v.z - mu, dw = v.w - mu;
    float ss = dx * dx + dy * dy + dz * dz + dw * dw;
    #pragma unroll
    for (int off = 32; off > 0; off >>= 1) ss += __shfl_down(ss, off, 64);
    if (lane == 0) red[wid] = ss;
    __syncthreads();
    float var = (red[0] + red[1] + red[2] + red[3]) * (1.0f / D_);
    float rs = rsqrtf(var + LN_EPS);

    const float4 g = ((const float4*)gamma)[tid];
    const float4 b = ((const float4*)beta)[tid];
    us4 o;
    o.x = f2bf(dx * rs * g.x + b.x);
    o.y = f2bf(dy * rs * g.y + b.y);
    o.z = f2bf(dz * rs * g.z + b.z);
    o.w = f2bf(dw * rs * g.w + b.w);
    ((us4*)(nb + (size_t)t * D_))[tid] = o;
}

// ---------------- K1b: W_enc fp32 -> bf16 ----------------
__global__ __launch_bounds__(256) void cvt_kernel(const float* __restrict__ W,
                                                  unsigned short* __restrict__ Wb) {
    const int tid = threadIdx.x;
    const size_t base = (size_t)blockIdx.x * 1024;
    #pragma unroll
    for (int j = 0; j < 4; j++) {
        size_t i = base + j * 256 + tid;
        float4 f = ((const float4*)W)[i];
        us4 o;
        o.x = f2bf(f.x); o.y = f2bf(f.y); o.z = f2bf(f.z); o.w = f2bf(f.w);
        ((us4*)Wb)[i] = o;
    }
}

// ---------------- K2: 256x256 bf16 MFMA GEMM, half-tile-death pipeline ----------------
// 512 threads = 8 waves (2M x 4N). Wave tile 128x64 (8x4 16x16 frags). BK=64.
// LDS: 2 buffers x (A 256x64 + B 256x64) bf16 = 128 KiB, 3-bit XOR swizzle.
// Per K-tile, 4 phases:
//   P1: ds_read A m0-3 (kk0+kk1) + B kk0 (12xb128); stage (t+1).B0 -> nxt; 16 MFMA kk0
//   P2: ds_read A m4-7 (kk0+kk1) + B kk1 (12xb128); stage (t+1).B1 -> nxt; 16 MFMA kk0
//   --- buf[cur] now fully dead (all operands in registers) ---
//   P3: stage (t+2).A0 -> cur; 16 MFMA kk1 (registers only)
//   P4: stage (t+2).A1 -> cur; 16 MFMA kk1; vmcnt(4) (leaves t+2 A in flight)
// Counted vmcnt never drains to 0 (T4); setprio around MFMA clusters (T5);
// XCD-swizzled blockIdx (T1).
__global__ __launch_bounds__(512, 1) void gemm_kernel(const unsigned short* __restrict__ A,
                                                      const unsigned short* __restrict__ B,
                                                      unsigned short* __restrict__ L) {
    __shared__ unsigned short lds[2][2][256][64];
    const int tid = threadIdx.x;
    const int lane = tid & 63;
    const int w = tid >> 6;
    const int wm = w >> 2, wn = w & 3;

    // XCD-aware swizzle: nwg=1024=8*128; XCD x gets col-blocks 8x..8x+7 over all rows
    const int lin = blockIdx.x;
    const int swz = (lin & 7) * 128 + (lin >> 3);
    const int col0 = (swz >> 4) * 256;   // dict cols (64 col-blocks)
    const int row0 = (swz & 15) * 256;   // token rows (16 row-blocks)

    f32x4 acc[8][4] = {};

    auto stage = [&](int b, int mat, const unsigned short* __restrict__ G,
                     int rbase, int k0, int h) {
        unsigned short* plane = &lds[b][mat][0][0];
        #pragma unroll
        for (int i = 0; i < 2; i++) {
            const int cb = h * 1024 + i * 512 + w * 64;   // wave-uniform chunk base
            const int c = cb + lane;
            const int r = c >> 3, sl = c & 7, g = sl ^ (r & 7);
            gl2lds16(G + (size_t)(rbase + r) * 1024 + k0 + g * 8, plane + (size_t)cb * 8);
        }
    };

    // prologue: tile0 full (buf0, 8 loads) + tile1 A halves (buf1, 4 loads)
    stage(0, 0, A, row0, 0, 0);
    stage(0, 0, A, row0, 0, 1);
    stage(0, 1, B, col0, 0, 0);
    stage(0, 1, B, col0, 0, 1);
    stage(1, 0, A, row0, 64, 0);
    stage(1, 0, A, row0, 64, 1);
    asm volatile("s_waitcnt vmcnt(4)" ::: "memory");   // tile0 landed; tile1 A in flight
    __builtin_amdgcn_s_barrier();
    __builtin_amdgcn_sched_barrier(0);
    asm volatile("" ::: "memory");

    const int arow = wm * 128 + (lane & 15);
    const int brow = wn * 64 + (lane & 15);
    const int kg = lane >> 4;

    for (int t = 0; t < 16; t++) {
        const int cur = t & 1, nxt = cur ^ 1;
        const int kb1 = ((t + 1) & 15) * 64;   // next tile K offset (wrap keeps loop uniform)
        const int kb2 = ((t + 2) & 15) * 64;   // next-next tile K offset

        bf16x8 a0k0[4], a0k1[4], a1k0[4], a1k1[4], bk0[4], bk1[4];

        // ======== P1: read A m0-3 (both kk) + B kk0; stage (t+1).B0; MFMA m0-3 kk0
        #pragma unroll
        for (int m = 0; m < 4; m++) {
            const int r = arow + m * 16;
            a0k0[m] = *(const bf16x8*)&lds[cur][0][r][(kg ^ (r & 7)) * 8];
            a0k1[m] = *(const bf16x8*)&lds[cur][0][r][((4 + kg) ^ (r & 7)) * 8];
        }
        #pragma unroll
        for (int n = 0; n < 4; n++) {
            const int r = brow + n * 16;
            bk0[n] = *(const bf16x8*)&lds[cur][1][r][(kg ^ (r & 7)) * 8];
        }
        stage(nxt, 1, B, col0, kb1, 0);
        __builtin_amdgcn_s_barrier();
        asm volatile("s_waitcnt lgkmcnt(0)" ::: "memory");
        __builtin_amdgcn_sched_barrier(0);
        __builtin_amdgcn_s_setprio(1);
        #pragma unroll
        for (int m = 0; m < 4; m++)
            #pragma unroll
            for (int n = 0; n < 4; n++)
                acc[m][n] = __builtin_amdgcn_mfma_f32_16x16x32_bf16(a0k0[m], bk0[n], acc[m][n], 0, 0, 0);
        __builtin_amdgcn_s_setprio(0);
        __builtin_amdgcn_s_barrier();
        asm volatile("" ::: "memory");

        // ======== P2: read A m4-7 (both kk) + B kk1; stage (t+1).B1; MFMA m4-7 kk0
        #pragma unroll
        for (int m = 0; m < 4; m++) {
            const int r = arow + 64 + m * 16;
            a1k0[m] = *(const bf16x8*)&lds[cur][0][r][(kg ^ (r & 7)) * 8];
            a1k1[m] = *(const bf16x8*)&lds[cur][0][r][((4 + kg) ^ (r & 7)) * 8];
        }
        #pragma unroll
        for (int n = 0; n < 4; n++) {
            const int r = brow + n * 16;
            bk1[n] = *(const bf16x8*)&lds[cur][1][r][((4 + kg) ^ (r & 7)) * 8];
        }
        stage(nxt, 1, B, col0, kb1, 1);
        __builtin_amdgcn_s_barrier();
        asm volatile("s_waitcnt lgkmcnt(0)" ::: "memory");
        __builtin_amdgcn_sched_barrier(0);
        __builtin_amdgcn_s_setprio(1);
        #pragma unroll
        for (int m = 0; m < 4; m++)
            #pragma unroll
            for (int n = 0; n < 4; n++)
                acc[4 + m][n] = __builtin_amdgcn_mfma_f32_16x16x32_bf16(a1k0[m], bk0[n], acc[4 + m][n], 0, 0, 0);
        __builtin_amdgcn_s_setprio(0);
        __builtin_amdgcn_s_barrier();     // after this barrier buf[cur] is dead
        asm volatile("" ::: "memory");

        // ======== P3: stage (t+2).A0 into buf[cur]; MFMA m0-3 kk1 (registers only)
        stage(cur, 0, A, row0, kb2, 0);
        __builtin_amdgcn_s_setprio(1);
        #pragma unroll
        for (int m = 0; m < 4; m++)
            #pragma unroll
            for (int n = 0; n < 4; n++)
                acc[m][n] = __builtin_amdgcn_mfma_f32_16x16x32_bf16(a0k1[m], bk1[n], acc[m][n], 0, 0, 0);
        __builtin_amdgcn_s_setprio(0);
        __builtin_amdgcn_s_barrier();
        asm volatile("" ::: "memory");

        // ======== P4: stage (t+2).A1; MFMA m4-7 kk1; vmcnt(4) gate for next tile
        stage(cur, 0, A, row0, kb2, 1);
        __builtin_amdgcn_s_setprio(1);
        #pragma unroll
        for (int m = 0; m < 4; m++)
            #pragma unroll
            for (int n = 0; n < 4; n++)
                acc[4 + m][n] = __builtin_amdgcn_mfma_f32_16x16x32_bf16(a1k1[m], bk1[n], acc[4 + m][n], 0, 0, 0);
        __builtin_amdgcn_s_setprio(0);
        asm volatile("s_waitcnt vmcnt(4)" ::: "memory");  // (t+1) fully landed; (t+2).A in flight
        __builtin_amdgcn_s_barrier();
        __builtin_amdgcn_sched_barrier(0);
        asm volatile("" ::: "memory");
    }

    // epilogue: C/D layout col=lane&15, row=(lane>>4)*4+reg
    #pragma unroll
    for (int m = 0; m < 8; m++) {
        const int rb = row0 + wm * 128 + m * 16 + (lane >> 4) * 4;
        #pragma unroll
        for (int n = 0; n < 4; n++) {
            const int col = col0 + wn * 64 + n * 16 + (lane & 15);
            #pragma unroll
            for (int r = 0; r < 4; r++)
                L[(size_t)(rb + r) * DICT_ + col] = f2bf(acc[m][n][r]);
        }
    }
}

// ---------------- K3: per-token top-12 candidates from bf16 logits ----------------
__global__ __launch_bounds__(256) void cand_kernel(const unsigned short* __restrict__ L,
                                                   int* __restrict__ cand) {
    const int token = blockIdx.x;
    const int tid = threadIdx.x;
    const unsigned short* row = L + (size_t)token * DICT_;

    float v[5];
    int id[5];
    #pragma unroll
    for (int j = 0; j < 5; j++) { v[j] = -FLT_MAX; id[j] = -1; }

    for (int j = 0; j < 8; j++) {
        const int fi = j * 256 + tid;            // 16B group index (2048 per row)
        const us8 u = *(const us8*)&row[fi * 8];
        #pragma unroll
        for (int e = 0; e < 8; e++) {
            const float f = bf2f(u[e]);
            if (f > v[4]) {
                v[4] = f; id[4] = fi * 8 + e;
                #pragma unroll
                for (int q = 4; q > 0; q--) {
                    if (v[q] > v[q - 1]) {
                        float tv = v[q]; v[q] = v[q - 1]; v[q - 1] = tv;
                        int ti = id[q]; id[q] = id[q - 1]; id[q - 1] = ti;
                    }
                }
            }
        }
    }

    __shared__ float hv[256];
    __shared__ int hi[256];
    __shared__ int hp[256];
    __shared__ int wt;
    hv[tid] = v[0];
    hi[tid] = id[0];
    hp[tid] = 0;

    for (int round = 0; round < NCAND; round++) {
        __syncthreads();
        if (tid < 64) {
            float bv = hv[tid]; int bt = tid;
            #pragma unroll
            for (int q = 1; q < 4; q++) {
                const int t2 = tid + q * 64;
                const float v2 = hv[t2];
                if (v2 > bv || (v2 == bv && t2 < bt)) { bv = v2; bt = t2; }
            }
            #pragma unroll
            for (int off = 32; off > 0; off >>= 1) {
                const float ov = __shfl_down(bv, off, 64);
                const int ot = __shfl_down(bt, off, 64);
                if (ov > bv || (ov == bv && ot < bt)) { bv = ov; bt = ot; }
            }
            if (tid == 0) wt = bt;
        }
        __syncthreads();
        if (tid == wt) {
            cand[(size_t)token * NCAND + round] = hi[tid];
            const int p = hp[tid] + 1;
            hp[tid] = p;
            if (p < 5) { hv[tid] = v[p]; hi[tid] = id[p]; }
            else { hv[tid] = -FLT_MAX; hi[tid] = -1; }
        }
    }
}

// ---------------- K4: exact fp32 refine of 12 candidates -> top-8 sel ----------------
__global__ __launch_bounds__(256) void refine_kernel(const float* __restrict__ x,
                                                     const float* __restrict__ gamma,
                                                     const float* __restrict__ beta,
                                                     const float* __restrict__ Wenc,
                                                     const int* __restrict__ cand,
                                                     float* __restrict__ sel_val,
                                                     int* __restrict__ sel_idx) {
    const int token = blockIdx.x;
    const int tid = threadIdx.x;
    const int lane = tid & 63;
    const int w = tid >> 6;

    __shared__ float red[4];
    __shared__ float ln[D_];

    const float4 v = ((const float4*)(x + (size_t)token * D_))[tid];
    float s = v.x + v.y + v.z + v.w;
    #pragma unroll
    for (int off = 32; off > 0; off >>= 1) s += __shfl_down(s, off, 64);
    if (lane == 0) red[w] = s;
    __syncthreads();
    float mu = (red[0] + red[1] + red[2] + red[3]) * (1.0f / D_);
    __syncthreads();
    float dx = v.x - mu, dy = v.y - mu, dz = v.z - mu, dw = v.w - mu;
    float ss = dx * dx + dy * dy + dz * dz + dw * dw;
    #pragma unroll
    for (int off = 32; off > 0; off >>= 1) ss += __shfl_down(ss, off, 64);
    if (lane == 0) red[w] = ss;
    __syncthreads();
    float var = (red[0] + red[1] + red[2] + red[3]) * (1.0f / D_);
    float rs = rsqrtf(var + LN_EPS);
    const float4 g = ((const float4*)gamma)[tid];
    const float4 b = ((const float4*)beta)[tid];
    float4 o;
    o.x = dx * rs * g.x + b.x;
    o.y = dy * rs * g.y + b.y;
    o.z = dz * rs * g.z + b.z;
    o.w = dw * rs * g.w + b.w;
    ((float4*)ln)[tid] = o;
    __syncthreads();

    __shared__ float dv[NCAND];
    __shared__ int di_s[NCAND];
    for (int c = w; c < NCAND; c += 4) {
        const int di = cand[(size_t)token * NCAND + c];
        const float4* wr = (const float4*)(Wenc + (size_t)di * D_);
        float acc = 0.f;
        #pragma unroll
        for (int j = 0; j < 4; j++) {
            const float4 q = wr[j * 64 + lane];
            const float4 p = ((const float4*)ln)[j * 64 + lane];
            acc += q.x * p.x + q.y * p.y + q.z * p.z + q.w * p.w;
        }
        #pragma unroll
        for (int off = 32; off > 0; off >>= 1) acc += __shfl_down(acc, off, 64);
        if (lane == 0) { dv[c] = acc; di_s[c] = di; }
    }
    __syncthreads();

    __shared__ float wv[TOPK];
    __shared__ int wi[TOPK];
    if (tid == 0) {
        unsigned int used = 0;
        for (int p = 0; p < TOPK; p++) {
            float bv = -FLT_MAX; int bc = -1;
            for (int c = 0; c < NCAND; c++) {
                if (used & (1u << c)) continue;
                const float cv = dv[c];
                if (cv > bv || (cv == bv && di_s[c] < ((bc >= 0) ? di_s[bc] : 0x7fffffff))) { bv = cv; bc = c; }
            }
            used |= 1u << bc;
            wv[p] = dv[bc]; wi[p] = di_s[bc];
        }
    }
    __syncthreads();
    if (tid < TOPK) {
        sel_val[(size_t)token * TOPK + tid] = wv[tid];
        sel_idx[(size_t)token * TOPK + tid] = wi[tid];
    }
}

// ---------------- K5: fused sparse-row writer + reconstruction ----------------
__global__ __launch_bounds__(256) void sparse_recon_kernel(const float* __restrict__ sel_val,
                                                           const int* __restrict__ sel_idx,
                                                           const float* __restrict__ Wdict,
                                                           float* __restrict__ sparse,
                                                           float* __restrict__ recon) {
    const int token = blockIdx.x;
    const int tid = threadIdx.x;
    __shared__ float v8[TOPK];
    __shared__ int i8[TOPK];
    if (tid < TOPK) {
        v8[tid] = sel_val[(size_t)token * TOPK + tid];
        i8[tid] = sel_idx[(size_t)token * TOPK + tid];
    }
    __syncthreads();

    // issue recon loads early (latency hides under the store stream)
    float4 wr[TOPK];
    #pragma unroll
    for (int j = 0; j < TOPK; j++)
        wr[j] = ((const float4*)(Wdict + (size_t)i8[j] * D_))[tid];

    f32x4* row = (f32x4*)(sparse + (size_t)token * DICT_);
    #pragma unroll
    for (int q = 0; q < 16; q++) {
        const int grp = q * 256 + tid;       // 4096 groups: full row
        const int base = grp * 4;
        f32x4 o = {0.f, 0.f, 0.f, 0.f};
        #pragma unroll
        for (int j = 0; j < TOPK; j++) {
            const int rel = i8[j] - base;
            o.x = (rel == 0) ? v8[j] : o.x;
            o.y = (rel == 1) ? v8[j] : o.y;
            o.z = (rel == 2) ? v8[j] : o.z;
            o.w = (rel == 3) ? v8[j] : o.w;
        }
        __builtin_nontemporal_store(o, row + grp);
    }

    float4 acc = {0.f, 0.f, 0.f, 0.f};
    #pragma unroll
    for (int j = 0; j < TOPK; j++) {
        const float c = v8[j];
        acc.x = fmaf(c, wr[j].x, acc.x);
        acc.y = fmaf(c, wr[j].y, acc.y);
        acc.z = fmaf(c, wr[j].z, acc.z);
        acc.w = fmaf(c, wr[j].w, acc.w);
    }
    ((float4*)(recon + (size_t)token * D_))[tid] = acc;
}

extern "C" void kernel_launch(void* const* d_in, const int* in_sizes, int n_in,
                              void* d_out, int out_size, void* d_ws, size_t ws_size,
                              hipStream_t stream) {
    const float* x = (const float*)d_in[0];
    const float* gamma = (const float*)d_in[1];
    const float* beta = (const float*)d_in[2];
    const float* Wenc = (const float*)d_in[3];
    const float* Wdict = (const float*)d_in[4];

    float* recon = (float*)d_out;
    float* sparse = (float*)d_out + (size_t)NTOK * D_;

    // all scratch in d_ws (~176.5 MB)
    unsigned short* Lg = (unsigned short*)d_ws;                   // bf16 logits, 134 MB
    unsigned short* We = Lg + (size_t)NTOK * DICT_;               // bf16 W_enc, 33.5 MB
    unsigned short* Nb = We + (size_t)DICT_ * D_;                 // bf16 normed, 8 MB
    int* cand = (int*)(Nb + (size_t)NTOK * D_);                   // 4096*12 int
    float* sel_val = (float*)(cand + (size_t)NTOK * NCAND);       // 4096*8 f32
    int* sel_idx = (int*)(sel_val + (size_t)NTOK * TOPK);         // 4096*8 int

    ln_kernel<<<NTOK, 256, 0, stream>>>(x, gamma, beta, Nb);
    cvt_kernel<<<DICT_ * D_ / 4096, 256, 0, stream>>>(Wenc, We);

    gemm_kernel<<<(DICT_ / 256) * (NTOK / 256), 512, 0, stream>>>(Nb, We, Lg);

    cand_kernel<<<NTOK, 256, 0, stream>>>(Lg, cand);

    refine_kernel<<<NTOK, 256, 0, stream>>>(x, gamma, beta, Wenc, cand,
                                            sel_val, sel_idx);

    sparse_recon_kernel<<<NTOK, 256, 0, stream>>>(sel_val, sel_idx, Wdict,
                                                  sparse, recon);
}

// Round 12
// 317.228 us; speedup vs baseline: 1.0284x; 1.0214x over previous
//
#include <hip/hip_runtime.h>
#include <hip/hip_bf16.h>
#include <cfloat>

#define NTOK 4096
#define D_ 1024
#define DICT_ 16384
#define TOPK 8
#define NCAND 12
#define NBLKSEL 16
#define LN_EPS 1e-5f

typedef __attribute__((ext_vector_type(8))) short bf16x8;
typedef __attribute__((ext_vector_type(4))) float f32x4;
typedef __attribute__((ext_vector_type(8))) unsigned short us8;
typedef __attribute__((ext_vector_type(4))) unsigned short us4;

__device__ __forceinline__ unsigned short f2bf(float f) {
    unsigned int u = __float_as_uint(f);
    u += 0x7fffu + ((u >> 16) & 1u);   // RNE
    return (unsigned short)(u >> 16);
}
__device__ __forceinline__ float bf2f(unsigned short u) {
    return __uint_as_float(((unsigned int)u) << 16);
}

__device__ __forceinline__ void gl2lds16(const void* gsrc, void* ldsdst) {
    __builtin_amdgcn_global_load_lds(
        (const __attribute__((address_space(1))) unsigned int*)gsrc,
        (__attribute__((address_space(3))) unsigned int*)ldsdst, 16, 0, 0);
}

// ---------------- K1: LayerNorm -> bf16 normed ----------------
__global__ __launch_bounds__(256) void ln_kernel(const float* __restrict__ x,
                                                 const float* __restrict__ gamma,
                                                 const float* __restrict__ beta,
                                                 unsigned short* __restrict__ nb) {
    int t = blockIdx.x;
    int tid = threadIdx.x;
    const float4 v = ((const float4*)(x + (size_t)t * D_))[tid];

    float s = v.x + v.y + v.z + v.w;
    #pragma unroll
    for (int off = 32; off > 0; off >>= 1) s += __shfl_down(s, off, 64);
    __shared__ float red[4];
    int wid = tid >> 6, lane = tid & 63;
    if (lane == 0) red[wid] = s;
    __syncthreads();
    float mu = (red[0] + red[1] + red[2] + red[3]) * (1.0f / D_);
    __syncthreads();

    float dx = v.x - mu, dy = v.y - mu, dz = v.z - mu, dw = v.w - mu;
    float ss = dx * dx + dy * dy + dz * dz + dw * dw;
    #pragma unroll
    for (int off = 32; off > 0; off >>= 1) ss += __shfl_down(ss, off, 64);
    if (lane == 0) red[wid] = ss;
    __syncthreads();
    float var = (red[0] + red[1] + red[2] + red[3]) * (1.0f / D_);
    float rs = rsqrtf(var + LN_EPS);

    const float4 g = ((const float4*)gamma)[tid];
    const float4 b = ((const float4*)beta)[tid];
    us4 o;
    o.x = f2bf(dx * rs * g.x + b.x);
    o.y = f2bf(dy * rs * g.y + b.y);
    o.z = f2bf(dz * rs * g.z + b.z);
    o.w = f2bf(dw * rs * g.w + b.w);
    ((us4*)(nb + (size_t)t * D_))[tid] = o;
}

// ---------------- K1b: W_enc fp32 -> bf16 ----------------
__global__ __launch_bounds__(256) void cvt_kernel(const float* __restrict__ W,
                                                  unsigned short* __restrict__ Wb) {
    const int tid = threadIdx.x;
    const size_t base = (size_t)blockIdx.x * 1024;
    #pragma unroll
    for (int j = 0; j < 4; j++) {
        size_t i = base + j * 256 + tid;
        float4 f = ((const float4*)W)[i];
        us4 o;
        o.x = f2bf(f.x); o.y = f2bf(f.y); o.z = f2bf(f.z); o.w = f2bf(f.w);
        ((us4*)Wb)[i] = o;
    }
}

// ---------------- K2: 256x256 bf16 MFMA GEMM (R9 known-good loop) + blockmax ----------------
// 512 threads = 8 waves (2M x 4N). Wave tile 128x64 (8x4 16x16 frags). BK=64.
// Epilogue additionally emits cbm[token][64] = per-(row, 256-col-block) fp32 max.
// Blockmax path uses ONLY statically-indexed fmax + shfl_xor (no insertion arrays:
// rule #20 / R7-R8 regression).
__global__ __launch_bounds__(512, 1) void gemm_kernel(const unsigned short* __restrict__ A,
                                                      const unsigned short* __restrict__ B,
                                                      unsigned short* __restrict__ L,
                                                      float* __restrict__ cbm) {
    __shared__ unsigned short lds[2][2][256][64];
    const int tid = threadIdx.x;
    const int lane = tid & 63;
    const int w = tid >> 6;
    const int wm = w >> 2, wn = w & 3;
    const int col0 = blockIdx.x * 256;   // dict cols
    const int row0 = blockIdx.y * 256;   // token rows

    f32x4 acc[8][4] = {};

    auto stage = [&](int b, int mat, const unsigned short* __restrict__ G,
                     int rbase, int k0, int h) {
        unsigned short* plane = &lds[b][mat][0][0];
        #pragma unroll
        for (int i = 0; i < 2; i++) {
            const int cb = h * 1024 + i * 512 + w * 64;   // wave-uniform chunk base
            const int c = cb + lane;
            const int r = c >> 3, sl = c & 7, g = sl ^ (r & 7);
            gl2lds16(G + (size_t)(rbase + r) * 1024 + k0 + g * 8, plane + (size_t)cb * 8);
        }
    };

    // prologue: stage tile 0 into buf 0
    stage(0, 0, A, row0, 0, 0);
    stage(0, 0, A, row0, 0, 1);
    stage(0, 1, B, col0, 0, 0);
    stage(0, 1, B, col0, 0, 1);

    const int arow = wm * 128 + (lane & 15);
    const int brow = wn * 64 + (lane & 15);
    const int kg = lane >> 4;

    for (int t = 0; t < 16; t++) {
        const int cur = t & 1, nxt = cur ^ 1;
        const int kn = ((t + 1) & 15) * 64;   // wrap-around keeps loop uniform

        // ---- phase 0: issue next A halves; wait tile t (leave 4 in flight); kk0, n={0,1}
        stage(nxt, 0, A, row0, kn, 0);
        stage(nxt, 0, A, row0, kn, 1);
        asm volatile("s_waitcnt vmcnt(4)" ::: "memory");
        __builtin_amdgcn_s_barrier();
        __builtin_amdgcn_sched_barrier(0);
        asm volatile("" ::: "memory");

        bf16x8 af[8];
        #pragma unroll
        for (int m = 0; m < 8; m++) {
            const int r = arow + m * 16;
            af[m] = *(const bf16x8*)&lds[cur][0][r][(kg ^ (r & 7)) * 8];
        }
        bf16x8 b0, b1;
        { const int r = brow;      b0 = *(const bf16x8*)&lds[cur][1][r][(kg ^ (r & 7)) * 8]; }
        { const int r = brow + 16; b1 = *(const bf16x8*)&lds[cur][1][r][(kg ^ (r & 7)) * 8]; }
        __builtin_amdgcn_s_setprio(1);
        #pragma unroll
        for (int m = 0; m < 8; m++) {
            acc[m][0] = __builtin_amdgcn_mfma_f32_16x16x32_bf16(af[m], b0, acc[m][0], 0, 0, 0);
            acc[m][1] = __builtin_amdgcn_mfma_f32_16x16x32_bf16(af[m], b1, acc[m][1], 0, 0, 0);
        }
        __builtin_amdgcn_s_setprio(0);

        // ---- phase 1: issue next B halves; kk0, n={2,3}
        stage(nxt, 1, B, col0, kn, 0);
        stage(nxt, 1, B, col0, kn, 1);
        { const int r = brow + 32; b0 = *(const bf16x8*)&lds[cur][1][r][(kg ^ (r & 7)) * 8]; }
        { const int r = brow + 48; b1 = *(const bf16x8*)&lds[cur][1][r][(kg ^ (r & 7)) * 8]; }
        __builtin_amdgcn_s_setprio(1);
        #pragma unroll
        for (int m = 0; m < 8; m++) {
            acc[m][2] = __builtin_amdgcn_mfma_f32_16x16x32_bf16(af[m], b0, acc[m][2], 0, 0, 0);
            acc[m][3] = __builtin_amdgcn_mfma_f32_16x16x32_bf16(af[m], b1, acc[m][3], 0, 0, 0);
        }
        __builtin_amdgcn_s_setprio(0);

        // ---- phase 2: kk1, n={0,1}
        #pragma unroll
        for (int m = 0; m < 8; m++) {
            const int r = arow + m * 16;
            af[m] = *(const bf16x8*)&lds[cur][0][r][((4 + kg) ^ (r & 7)) * 8];
        }
        { const int r = brow;      b0 = *(const bf16x8*)&lds[cur][1][r][((4 + kg) ^ (r & 7)) * 8]; }
        { const int r = brow + 16; b1 = *(const bf16x8*)&lds[cur][1][r][((4 + kg) ^ (r & 7)) * 8]; }
        __builtin_amdgcn_s_setprio(1);
        #pragma unroll
        for (int m = 0; m < 8; m++) {
            acc[m][0] = __builtin_amdgcn_mfma_f32_16x16x32_bf16(af[m], b0, acc[m][0], 0, 0, 0);
            acc[m][1] = __builtin_amdgcn_mfma_f32_16x16x32_bf16(af[m], b1, acc[m][1], 0, 0, 0);
        }
        __builtin_amdgcn_s_setprio(0);

        // ---- phase 3: kk1, n={2,3}
        { const int r = brow + 32; b0 = *(const bf16x8*)&lds[cur][1][r][((4 + kg) ^ (r & 7)) * 8]; }
        { const int r = brow + 48; b1 = *(const bf16x8*)&lds[cur][1][r][((4 + kg) ^ (r & 7)) * 8]; }
        __builtin_amdgcn_s_setprio(1);
        #pragma unroll
        for (int m = 0; m < 8; m++) {
            acc[m][2] = __builtin_amdgcn_mfma_f32_16x16x32_bf16(af[m], b0, acc[m][2], 0, 0, 0);
            acc[m][3] = __builtin_amdgcn_mfma_f32_16x16x32_bf16(af[m], b1, acc[m][3], 0, 0, 0);
        }
        __builtin_amdgcn_s_setprio(0);

        __builtin_amdgcn_s_barrier();
        __builtin_amdgcn_sched_barrier(0);
        asm volatile("" ::: "memory");
    }

    // ---- blockmax: per-(m,r) row max over this thread's 16 cols, fully static ----
    float rmax[8][4];
    #pragma unroll
    for (int m = 0; m < 8; m++)
        #pragma unroll
        for (int r = 0; r < 4; r++)
            rmax[m][r] = fmaxf(fmaxf(acc[m][0][r], acc[m][1][r]),
                               fmaxf(acc[m][2][r], acc[m][3][r]));
    // butterfly over the 16 col-lanes (lane&15) -> row max over wn's 64 cols
    #pragma unroll
    for (int m = 0; m < 8; m++)
        #pragma unroll
        for (int r = 0; r < 4; r++) {
            float v = rmax[m][r];
            v = fmaxf(v, __shfl_xor(v, 1, 64));
            v = fmaxf(v, __shfl_xor(v, 2, 64));
            v = fmaxf(v, __shfl_xor(v, 4, 64));
            v = fmaxf(v, __shfl_xor(v, 8, 64));
            rmax[m][r] = v;
        }

    // drain in-flight wrap-around staging DMA, then reuse LDS for cross-wave max
    asm volatile("s_waitcnt vmcnt(0)" ::: "memory");
    __builtin_amdgcn_s_barrier();
    __builtin_amdgcn_sched_barrier(0);

    float* bm = (float*)&lds[0][0][0][0];   // [4 wn][256 rows] = 4 KB
    if ((lane & 15) == 0) {
        const int q = lane >> 4;
        #pragma unroll
        for (int m = 0; m < 8; m++)
            #pragma unroll
            for (int r = 0; r < 4; r++)
                bm[wn * 256 + wm * 128 + m * 16 + q * 4 + r] = rmax[m][r];
    }
    __syncthreads();
    if (tid < 256) {
        const float b0 = fmaxf(fmaxf(bm[tid], bm[256 + tid]),
                               fmaxf(bm[512 + tid], bm[768 + tid]));
        cbm[(size_t)(row0 + tid) * 64 + blockIdx.x] = b0;
    }

    // logits write: C/D layout col=lane&15, row=(lane>>4)*4+reg
    #pragma unroll
    for (int m = 0; m < 8; m++) {
        const int rb = row0 + wm * 128 + m * 16 + (lane >> 4) * 4;
        #pragma unroll
        for (int n = 0; n < 4; n++) {
            const int col = col0 + wn * 64 + n * 16 + (lane & 15);
            #pragma unroll
            for (int r = 0; r < 4; r++)
                L[(size_t)(rb + r) * DICT_ + col] = f2bf(acc[m][n][r]);
        }
    }
}

// ---------------- K3: targeted top-12 candidates via top-16 blocks ----------------
// Deterministic: any value with <=15 values above it lies in the top-16 blocks
// by blockmax, so the bf16-top-12 of the 16-block union == full-scan top-12.
__global__ __launch_bounds__(256) void cand_kernel(const float* __restrict__ cbm,
                                                   const unsigned short* __restrict__ L,
                                                   int* __restrict__ cand) {
    const int token = blockIdx.x;
    const int tid = threadIdx.x;

    __shared__ int blksel[NBLKSEL];
    if (tid < 64) {
        float v = cbm[(size_t)token * 64 + tid];
        for (int round = 0; round < NBLKSEL; round++) {
            float bv = v; int bi = tid;
            #pragma unroll
            for (int off = 32; off > 0; off >>= 1) {
                const float ov = __shfl_xor(bv, off, 64);
                const int oi = __shfl_xor(bi, off, 64);
                if (ov > bv || (ov == bv && oi < bi)) { bv = ov; bi = oi; }
            }
            if (tid == 0) blksel[round] = bi;
            if (tid == bi) v = -FLT_MAX;
        }
    }
    __syncthreads();

    float v4[4]; int id4[4];
    #pragma unroll
    for (int j = 0; j < 4; j++) { v4[j] = -FLT_MAX; id4[j] = -1; }

    // pass 0: blocks 0..7 (all 256 threads), pass 1: blocks 8..15 (tid<128)
    #pragma unroll
    for (int pass = 0; pass < 2; pass++) {
        if (pass == 1 && tid >= 128) break;
        const int b = blksel[pass * 8 + (tid >> 5)];
        const int colbase = b * 256 + (tid & 31) * 8;
        const us8 u = *(const us8*)&L[(size_t)token * DICT_ + colbase];
        #pragma unroll
        for (int e = 0; e < 8; e++) {
            const float f = bf2f(u[e]);
            if (f > v4[3]) {
                v4[3] = f; id4[3] = colbase + e;
                #pragma unroll
                for (int q = 3; q > 0; q--) {
                    if (v4[q] > v4[q - 1]) {
                        float tf = v4[q]; v4[q] = v4[q - 1]; v4[q - 1] = tf;
                        int ti = id4[q]; id4[q] = id4[q - 1]; id4[q - 1] = ti;
                    }
                }
            }
        }
    }

    __shared__ float hv[256];
    __shared__ int hi[256];
    __shared__ int hp[256];
    __shared__ int wt;
    hv[tid] = v4[0];
    hi[tid] = id4[0];
    hp[tid] = 0;

    for (int round = 0; round < NCAND; round++) {
        __syncthreads();
        if (tid < 64) {
            float bv = hv[tid]; int bt = tid;
            #pragma unroll
            for (int q = 1; q < 4; q++) {
                const int t2 = tid + q * 64;
                const float v2 = hv[t2];
                if (v2 > bv || (v2 == bv && t2 < bt)) { bv = v2; bt = t2; }
            }
            #pragma unroll
            for (int off = 32; off > 0; off >>= 1) {
                const float ov = __shfl_down(bv, off, 64);
                const int ot = __shfl_down(bt, off, 64);
                if (ov > bv || (ov == bv && ot < bt)) { bv = ov; bt = ot; }
            }
            if (tid == 0) wt = bt;
        }
        __syncthreads();
        if (tid == wt) {
            cand[(size_t)token * NCAND + round] = hi[tid];
            const int p = hp[tid] + 1;
            hp[tid] = p;
            if (p < 4) { hv[tid] = v4[p]; hi[tid] = id4[p]; }
            else { hv[tid] = -FLT_MAX; hi[tid] = -1; }
        }
    }
}

// ---------------- K4: exact fp32 refine of 12 candidates -> top-8 sel ----------------
__global__ __launch_bounds__(256) void refine_kernel(const float* __restrict__ x,
                                                     const float* __restrict__ gamma,
                                                     const float* __restrict__ beta,
                                                     const float* __restrict__ Wenc,
                                                     const int* __restrict__ cand,
                                                     float* __restrict__ sel_val,
                                                     int* __restrict__ sel_idx) {
    const int token = blockIdx.x;
    const int tid = threadIdx.x;
    const int lane = tid & 63;
    const int w = tid >> 6;

    __shared__ float red[4];
    __shared__ float ln[D_];

    const float4 v = ((const float4*)(x + (size_t)token * D_))[tid];
    float s = v.x + v.y + v.z + v.w;
    #pragma unroll
    for (int off = 32; off > 0; off >>= 1) s += __shfl_down(s, off, 64);
    if (lane == 0) red[w] = s;
    __syncthreads();
    float mu = (red[0] + red[1] + red[2] + red[3]) * (1.0f / D_);
    __syncthreads();
    float dx = v.x - mu, dy = v.y - mu, dz = v.z - mu, dw = v.w - mu;
    float ss = dx * dx + dy * dy + dz * dz + dw * dw;
    #pragma unroll
    for (int off = 32; off > 0; off >>= 1) ss += __shfl_down(ss, off, 64);
    if (lane == 0) red[w] = ss;
    __syncthreads();
    float var = (red[0] + red[1] + red[2] + red[3]) * (1.0f / D_);
    float rs = rsqrtf(var + LN_EPS);
    const float4 g = ((const float4*)gamma)[tid];
    const float4 b = ((const float4*)beta)[tid];
    float4 o;
    o.x = dx * rs * g.x + b.x;
    o.y = dy * rs * g.y + b.y;
    o.z = dz * rs * g.z + b.z;
    o.w = dw * rs * g.w + b.w;
    ((float4*)ln)[tid] = o;
    __syncthreads();

    __shared__ float dv[NCAND];
    __shared__ int di_s[NCAND];
    for (int c = w; c < NCAND; c += 4) {
        const int di = cand[(size_t)token * NCAND + c];
        const float4* wr = (const float4*)(Wenc + (size_t)di * D_);
        float acc = 0.f;
        #pragma unroll
        for (int j = 0; j < 4; j++) {
            const float4 q = wr[j * 64 + lane];
            const float4 p = ((const float4*)ln)[j * 64 + lane];
            acc += q.x * p.x + q.y * p.y + q.z * p.z + q.w * p.w;
        }
        #pragma unroll
        for (int off = 32; off > 0; off >>= 1) acc += __shfl_down(acc, off, 64);
        if (lane == 0) { dv[c] = acc; di_s[c] = di; }
    }
    __syncthreads();

    __shared__ float wv[TOPK];
    __shared__ int wi[TOPK];
    if (tid == 0) {
        unsigned int used = 0;
        for (int p = 0; p < TOPK; p++) {
            float bv = -FLT_MAX; int bc = -1;
            for (int c = 0; c < NCAND; c++) {
                if (used & (1u << c)) continue;
                const float cv = dv[c];
                if (cv > bv || (cv == bv && di_s[c] < ((bc >= 0) ? di_s[bc] : 0x7fffffff))) { bv = cv; bc = c; }
            }
            used |= 1u << bc;
            wv[p] = dv[bc]; wi[p] = di_s[bc];
        }
    }
    __syncthreads();
    if (tid < TOPK) {
        sel_val[(size_t)token * TOPK + tid] = wv[tid];
        sel_idx[(size_t)token * TOPK + tid] = wi[tid];
    }
}

// ---------------- K5: fused sparse-row writer + reconstruction ----------------
__global__ __launch_bounds__(256) void sparse_recon_kernel(const float* __restrict__ sel_val,
                                                           const int* __restrict__ sel_idx,
                                                           const float* __restrict__ Wdict,
                                                           float* __restrict__ sparse,
                                                           float* __restrict__ recon) {
    const int token = blockIdx.x;
    const int tid = threadIdx.x;
    __shared__ float v8[TOPK];
    __shared__ int i8[TOPK];
    if (tid < TOPK) {
        v8[tid] = sel_val[(size_t)token * TOPK + tid];
        i8[tid] = sel_idx[(size_t)token * TOPK + tid];
    }
    __syncthreads();

    // issue recon loads early (latency hides under the store stream)
    float4 wr[TOPK];
    #pragma unroll
    for (int j = 0; j < TOPK; j++)
        wr[j] = ((const float4*)(Wdict + (size_t)i8[j] * D_))[tid];

    f32x4* row = (f32x4*)(sparse + (size_t)token * DICT_);
    #pragma unroll
    for (int q = 0; q < 16; q++) {
        const int grp = q * 256 + tid;       // 4096 groups: full row
        const int base = grp * 4;
        f32x4 o = {0.f, 0.f, 0.f, 0.f};
        #pragma unroll
        for (int j = 0; j < TOPK; j++) {
            const int rel = i8[j] - base;
            o.x = (rel == 0) ? v8[j] : o.x;
            o.y = (rel == 1) ? v8[j] : o.y;
            o.z = (rel == 2) ? v8[j] : o.z;
            o.w = (rel == 3) ? v8[j] : o.w;
        }
        __builtin_nontemporal_store(o, row + grp);
    }

    float4 acc = {0.f, 0.f, 0.f, 0.f};
    #pragma unroll
    for (int j = 0; j < TOPK; j++) {
        const float c = v8[j];
        acc.x = fmaf(c, wr[j].x, acc.x);
        acc.y = fmaf(c, wr[j].y, acc.y);
        acc.z = fmaf(c, wr[j].z, acc.z);
        acc.w = fmaf(c, wr[j].w, acc.w);
    }
    ((float4*)(recon + (size_t)token * D_))[tid] = acc;
}

extern "C" void kernel_launch(void* const* d_in, const int* in_sizes, int n_in,
                              void* d_out, int out_size, void* d_ws, size_t ws_size,
                              hipStream_t stream) {
    const float* x = (const float*)d_in[0];
    const float* gamma = (const float*)d_in[1];
    const float* beta = (const float*)d_in[2];
    const float* Wenc = (const float*)d_in[3];
    const float* Wdict = (const float*)d_in[4];

    float* recon = (float*)d_out;
    float* sparse = (float*)d_out + (size_t)NTOK * D_;

    // scratch in d_ws (~178 MB)
    unsigned short* Lg = (unsigned short*)d_ws;                   // bf16 logits, 134 MB
    unsigned short* We = Lg + (size_t)NTOK * DICT_;               // bf16 W_enc, 33.5 MB
    unsigned short* Nb = We + (size_t)DICT_ * D_;                 // bf16 normed, 8 MB
    float* cbm = (float*)(Nb + (size_t)NTOK * D_);                // 4096*64 f32, 1 MB
    int* cand = (int*)(cbm + (size_t)NTOK * 64);                  // 4096*12 int
    float* sel_val = (float*)(cand + (size_t)NTOK * NCAND);       // 4096*8 f32
    int* sel_idx = (int*)(sel_val + (size_t)NTOK * TOPK);         // 4096*8 int

    ln_kernel<<<NTOK, 256, 0, stream>>>(x, gamma, beta, Nb);
    cvt_kernel<<<DICT_ * D_ / 4096, 256, 0, stream>>>(Wenc, We);

    dim3 gg(DICT_ / 256, NTOK / 256);
    gemm_kernel<<<gg, 512, 0, stream>>>(Nb, We, Lg, cbm);

    cand_kernel<<<NTOK, 256, 0, stream>>>(cbm, Lg, cand);

    refine_kernel<<<NTOK, 256, 0, stream>>>(x, gamma, beta, Wenc, cand,
                                            sel_val, sel_idx);

    sparse_recon_kernel<<<NTOK, 256, 0, stream>>>(sel_val, sel_idx, Wdict,
                                                  sparse, recon);
}

// Round 13
// 303.271 us; speedup vs baseline: 1.0757x; 1.0460x over previous
//
#include <hip/hip_runtime.h>
#include <hip/hip_bf16.h>
#include <cfloat>

#define NTOK 4096
#define D_ 1024
#define DICT_ 16384
#define TOPK 8
#define NCAND 12
#define NBLKSEL 16
#define LN_EPS 1e-5f

typedef __attribute__((ext_vector_type(8))) short bf16x8;
typedef __attribute__((ext_vector_type(4))) float f32x4;
typedef __attribute__((ext_vector_type(8))) unsigned short us8;
typedef __attribute__((ext_vector_type(4))) unsigned short us4;

__device__ __forceinline__ unsigned short f2bf(float f) {
    unsigned int u = __float_as_uint(f);
    u += 0x7fffu + ((u >> 16) & 1u);   // RNE
    return (unsigned short)(u >> 16);
}
__device__ __forceinline__ float bf2f(unsigned short u) {
    return __uint_as_float(((unsigned int)u) << 16);
}

__device__ __forceinline__ void gl2lds16(const void* gsrc, void* ldsdst) {
    __builtin_amdgcn_global_load_lds(
        (const __attribute__((address_space(1))) unsigned int*)gsrc,
        (__attribute__((address_space(3))) unsigned int*)ldsdst, 16, 0, 0);
}

// ---------------- K1: LayerNorm -> bf16 normed ----------------
__global__ __launch_bounds__(256) void ln_kernel(const float* __restrict__ x,
                                                 const float* __restrict__ gamma,
                                                 const float* __restrict__ beta,
                                                 unsigned short* __restrict__ nb) {
    int t = blockIdx.x;
    int tid = threadIdx.x;
    const float4 v = ((const float4*)(x + (size_t)t * D_))[tid];

    float s = v.x + v.y + v.z + v.w;
    #pragma unroll
    for (int off = 32; off > 0; off >>= 1) s += __shfl_down(s, off, 64);
    __shared__ float red[4];
    int wid = tid >> 6, lane = tid & 63;
    if (lane == 0) red[wid] = s;
    __syncthreads();
    float mu = (red[0] + red[1] + red[2] + red[3]) * (1.0f / D_);
    __syncthreads();

    float dx = v.x - mu, dy = v.y - mu, dz = v.z - mu, dw = v.w - mu;
    float ss = dx * dx + dy * dy + dz * dz + dw * dw;
    #pragma unroll
    for (int off = 32; off > 0; off >>= 1) ss += __shfl_down(ss, off, 64);
    if (lane == 0) red[wid] = ss;
    __syncthreads();
    float var = (red[0] + red[1] + red[2] + red[3]) * (1.0f / D_);
    float rs = rsqrtf(var + LN_EPS);

    const float4 g = ((const float4*)gamma)[tid];
    const float4 b = ((const float4*)beta)[tid];
    us4 o;
    o.x = f2bf(dx * rs * g.x + b.x);
    o.y = f2bf(dy * rs * g.y + b.y);
    o.z = f2bf(dz * rs * g.z + b.z);
    o.w = f2bf(dw * rs * g.w + b.w);
    ((us4*)(nb + (size_t)t * D_))[tid] = o;
}

// ---------------- K1b: W_enc fp32 -> bf16 ----------------
__global__ __launch_bounds__(256) void cvt_kernel(const float* __restrict__ W,
                                                  unsigned short* __restrict__ Wb) {
    const int tid = threadIdx.x;
    const size_t base = (size_t)blockIdx.x * 1024;
    #pragma unroll
    for (int j = 0; j < 4; j++) {
        size_t i = base + j * 256 + tid;
        float4 f = ((const float4*)W)[i];
        us4 o;
        o.x = f2bf(f.x); o.y = f2bf(f.y); o.z = f2bf(f.z); o.w = f2bf(f.w);
        ((us4*)Wb)[i] = o;
    }
}

// ---------------- K2: 256x256 bf16 MFMA GEMM + blockmax + streamed zero-fill ----------------
// R9 known-good K-loop. Epilogue: logits (bf16), per-(row,block) max, and this
// block's 256 KB slice of the sparse output zero-filled with NT stores -- the
// zeros ride the GEMM's idle write BW instead of a separate 55us kernel.
__global__ __launch_bounds__(512, 1) void gemm_kernel(const unsigned short* __restrict__ A,
                                                      const unsigned short* __restrict__ B,
                                                      unsigned short* __restrict__ L,
                                                      float* __restrict__ cbm,
                                                      float* __restrict__ Z) {
    __shared__ unsigned short lds[2][2][256][64];
    const int tid = threadIdx.x;
    const int lane = tid & 63;
    const int w = tid >> 6;
    const int wm = w >> 2, wn = w & 3;
    const int col0 = blockIdx.x * 256;   // dict cols
    const int row0 = blockIdx.y * 256;   // token rows

    f32x4 acc[8][4] = {};

    auto stage = [&](int b, int mat, const unsigned short* __restrict__ G,
                     int rbase, int k0, int h) {
        unsigned short* plane = &lds[b][mat][0][0];
        #pragma unroll
        for (int i = 0; i < 2; i++) {
            const int cb = h * 1024 + i * 512 + w * 64;   // wave-uniform chunk base
            const int c = cb + lane;
            const int r = c >> 3, sl = c & 7, g = sl ^ (r & 7);
            gl2lds16(G + (size_t)(rbase + r) * 1024 + k0 + g * 8, plane + (size_t)cb * 8);
        }
    };

    // prologue: stage tile 0 into buf 0
    stage(0, 0, A, row0, 0, 0);
    stage(0, 0, A, row0, 0, 1);
    stage(0, 1, B, col0, 0, 0);
    stage(0, 1, B, col0, 0, 1);

    const int arow = wm * 128 + (lane & 15);
    const int brow = wn * 64 + (lane & 15);
    const int kg = lane >> 4;

    for (int t = 0; t < 16; t++) {
        const int cur = t & 1, nxt = cur ^ 1;
        const int kn = ((t + 1) & 15) * 64;   // wrap-around keeps loop uniform

        // ---- phase 0: issue next A halves; wait tile t (leave 4 in flight); kk0, n={0,1}
        stage(nxt, 0, A, row0, kn, 0);
        stage(nxt, 0, A, row0, kn, 1);
        asm volatile("s_waitcnt vmcnt(4)" ::: "memory");
        __builtin_amdgcn_s_barrier();
        __builtin_amdgcn_sched_barrier(0);
        asm volatile("" ::: "memory");

        bf16x8 af[8];
        #pragma unroll
        for (int m = 0; m < 8; m++) {
            const int r = arow + m * 16;
            af[m] = *(const bf16x8*)&lds[cur][0][r][(kg ^ (r & 7)) * 8];
        }
        bf16x8 b0, b1;
        { const int r = brow;      b0 = *(const bf16x8*)&lds[cur][1][r][(kg ^ (r & 7)) * 8]; }
        { const int r = brow + 16; b1 = *(const bf16x8*)&lds[cur][1][r][(kg ^ (r & 7)) * 8]; }
        __builtin_amdgcn_s_setprio(1);
        #pragma unroll
        for (int m = 0; m < 8; m++) {
            acc[m][0] = __builtin_amdgcn_mfma_f32_16x16x32_bf16(af[m], b0, acc[m][0], 0, 0, 0);
            acc[m][1] = __builtin_amdgcn_mfma_f32_16x16x32_bf16(af[m], b1, acc[m][1], 0, 0, 0);
        }
        __builtin_amdgcn_s_setprio(0);

        // ---- phase 1: issue next B halves; kk0, n={2,3}
        stage(nxt, 1, B, col0, kn, 0);
        stage(nxt, 1, B, col0, kn, 1);
        { const int r = brow + 32; b0 = *(const bf16x8*)&lds[cur][1][r][(kg ^ (r & 7)) * 8]; }
        { const int r = brow + 48; b1 = *(const bf16x8*)&lds[cur][1][r][(kg ^ (r & 7)) * 8]; }
        __builtin_amdgcn_s_setprio(1);
        #pragma unroll
        for (int m = 0; m < 8; m++) {
            acc[m][2] = __builtin_amdgcn_mfma_f32_16x16x32_bf16(af[m], b0, acc[m][2], 0, 0, 0);
            acc[m][3] = __builtin_amdgcn_mfma_f32_16x16x32_bf16(af[m], b1, acc[m][3], 0, 0, 0);
        }
        __builtin_amdgcn_s_setprio(0);

        // ---- phase 2: kk1, n={0,1}
        #pragma unroll
        for (int m = 0; m < 8; m++) {
            const int r = arow + m * 16;
            af[m] = *(const bf16x8*)&lds[cur][0][r][((4 + kg) ^ (r & 7)) * 8];
        }
        { const int r = brow;      b0 = *(const bf16x8*)&lds[cur][1][r][((4 + kg) ^ (r & 7)) * 8]; }
        { const int r = brow + 16; b1 = *(const bf16x8*)&lds[cur][1][r][((4 + kg) ^ (r & 7)) * 8]; }
        __builtin_amdgcn_s_setprio(1);
        #pragma unroll
        for (int m = 0; m < 8; m++) {
            acc[m][0] = __builtin_amdgcn_mfma_f32_16x16x32_bf16(af[m], b0, acc[m][0], 0, 0, 0);
            acc[m][1] = __builtin_amdgcn_mfma_f32_16x16x32_bf16(af[m], b1, acc[m][1], 0, 0, 0);
        }
        __builtin_amdgcn_s_setprio(0);

        // ---- phase 3: kk1, n={2,3}
        { const int r = brow + 32; b0 = *(const bf16x8*)&lds[cur][1][r][((4 + kg) ^ (r & 7)) * 8]; }
        { const int r = brow + 48; b1 = *(const bf16x8*)&lds[cur][1][r][((4 + kg) ^ (r & 7)) * 8]; }
        __builtin_amdgcn_s_setprio(1);
        #pragma unroll
        for (int m = 0; m < 8; m++) {
            acc[m][2] = __builtin_amdgcn_mfma_f32_16x16x32_bf16(af[m], b0, acc[m][2], 0, 0, 0);
            acc[m][3] = __builtin_amdgcn_mfma_f32_16x16x32_bf16(af[m], b1, acc[m][3], 0, 0, 0);
        }
        __builtin_amdgcn_s_setprio(0);

        __builtin_amdgcn_s_barrier();
        __builtin_amdgcn_sched_barrier(0);
        asm volatile("" ::: "memory");
    }

    // ---- blockmax: per-(m,r) row max over this thread's 16 cols, fully static ----
    float rmax[8][4];
    #pragma unroll
    for (int m = 0; m < 8; m++)
        #pragma unroll
        for (int r = 0; r < 4; r++)
            rmax[m][r] = fmaxf(fmaxf(acc[m][0][r], acc[m][1][r]),
                               fmaxf(acc[m][2][r], acc[m][3][r]));
    #pragma unroll
    for (int m = 0; m < 8; m++)
        #pragma unroll
        for (int r = 0; r < 4; r++) {
            float v = rmax[m][r];
            v = fmaxf(v, __shfl_xor(v, 1, 64));
            v = fmaxf(v, __shfl_xor(v, 2, 64));
            v = fmaxf(v, __shfl_xor(v, 4, 64));
            v = fmaxf(v, __shfl_xor(v, 8, 64));
            rmax[m][r] = v;
        }

    // drain in-flight wrap-around staging DMA, then reuse LDS for cross-wave max
    asm volatile("s_waitcnt vmcnt(0)" ::: "memory");
    __builtin_amdgcn_s_barrier();
    __builtin_amdgcn_sched_barrier(0);

    float* bm = (float*)&lds[0][0][0][0];   // [4 wn][256 rows] = 4 KB
    if ((lane & 15) == 0) {
        const int q = lane >> 4;
        #pragma unroll
        for (int m = 0; m < 8; m++)
            #pragma unroll
            for (int r = 0; r < 4; r++)
                bm[wn * 256 + wm * 128 + m * 16 + q * 4 + r] = rmax[m][r];
    }
    __syncthreads();
    if (tid < 256) {
        const float b0 = fmaxf(fmaxf(bm[tid], bm[256 + tid]),
                               fmaxf(bm[512 + tid], bm[768 + tid]));
        cbm[(size_t)(row0 + tid) * 64 + blockIdx.x] = b0;
    }

    // logits write: C/D layout col=lane&15, row=(lane>>4)*4+reg
    #pragma unroll
    for (int m = 0; m < 8; m++) {
        const int rb = row0 + wm * 128 + m * 16 + (lane >> 4) * 4;
        #pragma unroll
        for (int n = 0; n < 4; n++) {
            const int col = col0 + wn * 64 + n * 16 + (lane & 15);
            #pragma unroll
            for (int r = 0; r < 4; r++)
                L[(size_t)(rb + r) * DICT_ + col] = f2bf(acc[m][n][r]);
        }
    }

    // ---- streamed zero-fill of this block's 256 KB slice of the sparse output ----
    // (rides the GEMM's idle write BW; patch_recon later writes the 8 values/token)
    {
        const f32x4 z = {0.f, 0.f, 0.f, 0.f};
        f32x4* zrow = (f32x4*)(Z + (size_t)(blockIdx.y * 64 + blockIdx.x) * 65536);
        #pragma unroll
        for (int i = 0; i < 32; i++)
            __builtin_nontemporal_store(z, zrow + i * 512 + tid);
    }
}

// ---------------- K3: targeted top-12 candidates via top-16 blocks ----------------
__global__ __launch_bounds__(256) void cand_kernel(const float* __restrict__ cbm,
                                                   const unsigned short* __restrict__ L,
                                                   int* __restrict__ cand) {
    const int token = blockIdx.x;
    const int tid = threadIdx.x;

    __shared__ int blksel[NBLKSEL];
    if (tid < 64) {
        float v = cbm[(size_t)token * 64 + tid];
        for (int round = 0; round < NBLKSEL; round++) {
            float bv = v; int bi = tid;
            #pragma unroll
            for (int off = 32; off > 0; off >>= 1) {
                const float ov = __shfl_xor(bv, off, 64);
                const int oi = __shfl_xor(bi, off, 64);
                if (ov > bv || (ov == bv && oi < bi)) { bv = ov; bi = oi; }
            }
            if (tid == 0) blksel[round] = bi;
            if (tid == bi) v = -FLT_MAX;
        }
    }
    __syncthreads();

    float v4[4]; int id4[4];
    #pragma unroll
    for (int j = 0; j < 4; j++) { v4[j] = -FLT_MAX; id4[j] = -1; }

    #pragma unroll
    for (int pass = 0; pass < 2; pass++) {
        if (pass == 1 && tid >= 128) break;
        const int b = blksel[pass * 8 + (tid >> 5)];
        const int colbase = b * 256 + (tid & 31) * 8;
        const us8 u = *(const us8*)&L[(size_t)token * DICT_ + colbase];
        #pragma unroll
        for (int e = 0; e < 8; e++) {
            const float f = bf2f(u[e]);
            if (f > v4[3]) {
                v4[3] = f; id4[3] = colbase + e;
                #pragma unroll
                for (int q = 3; q > 0; q--) {
                    if (v4[q] > v4[q - 1]) {
                        float tf = v4[q]; v4[q] = v4[q - 1]; v4[q - 1] = tf;
                        int ti = id4[q]; id4[q] = id4[q - 1]; id4[q - 1] = ti;
                    }
                }
            }
        }
    }

    __shared__ float hv[256];
    __shared__ int hi[256];
    __shared__ int hp[256];
    __shared__ int wt;
    hv[tid] = v4[0];
    hi[tid] = id4[0];
    hp[tid] = 0;

    for (int round = 0; round < NCAND; round++) {
        __syncthreads();
        if (tid < 64) {
            float bv = hv[tid]; int bt = tid;
            #pragma unroll
            for (int q = 1; q < 4; q++) {
                const int t2 = tid + q * 64;
                const float v2 = hv[t2];
                if (v2 > bv || (v2 == bv && t2 < bt)) { bv = v2; bt = t2; }
            }
            #pragma unroll
            for (int off = 32; off > 0; off >>= 1) {
                const float ov = __shfl_down(bv, off, 64);
                const int ot = __shfl_down(bt, off, 64);
                if (ov > bv || (ov == bv && ot < bt)) { bv = ov; bt = ot; }
            }
            if (tid == 0) wt = bt;
        }
        __syncthreads();
        if (tid == wt) {
            cand[(size_t)token * NCAND + round] = hi[tid];
            const int p = hp[tid] + 1;
            hp[tid] = p;
            if (p < 4) { hv[tid] = v4[p]; hi[tid] = id4[p]; }
            else { hv[tid] = -FLT_MAX; hi[tid] = -1; }
        }
    }
}

// ---------------- K4: exact fp32 refine of 12 candidates -> top-8 sel ----------------
__global__ __launch_bounds__(256) void refine_kernel(const float* __restrict__ x,
                                                     const float* __restrict__ gamma,
                                                     const float* __restrict__ beta,
                                                     const float* __restrict__ Wenc,
                                                     const int* __restrict__ cand,
                                                     float* __restrict__ sel_val,
                                                     int* __restrict__ sel_idx) {
    const int token = blockIdx.x;
    const int tid = threadIdx.x;
    const int lane = tid & 63;
    const int w = tid >> 6;

    __shared__ float red[4];
    __shared__ float ln[D_];

    const float4 v = ((const float4*)(x + (size_t)token * D_))[tid];
    float s = v.x + v.y + v.z + v.w;
    #pragma unroll
    for (int off = 32; off > 0; off >>= 1) s += __shfl_down(s, off, 64);
    if (lane == 0) red[w] = s;
    __syncthreads();
    float mu = (red[0] + red[1] + red[2] + red[3]) * (1.0f / D_);
    __syncthreads();
    float dx = v.x - mu, dy = v.y - mu, dz = v.z - mu, dw = v.w - mu;
    float ss = dx * dx + dy * dy + dz * dz + dw * dw;
    #pragma unroll
    for (int off = 32; off > 0; off >>= 1) ss += __shfl_down(ss, off, 64);
    if (lane == 0) red[w] = ss;
    __syncthreads();
    float var = (red[0] + red[1] + red[2] + red[3]) * (1.0f / D_);
    float rs = rsqrtf(var + LN_EPS);
    const float4 g = ((const float4*)gamma)[tid];
    const float4 b = ((const float4*)beta)[tid];
    float4 o;
    o.x = dx * rs * g.x + b.x;
    o.y = dy * rs * g.y + b.y;
    o.z = dz * rs * g.z + b.z;
    o.w = dw * rs * g.w + b.w;
    ((float4*)ln)[tid] = o;
    __syncthreads();

    __shared__ float dv[NCAND];
    __shared__ int di_s[NCAND];
    for (int c = w; c < NCAND; c += 4) {
        const int di = cand[(size_t)token * NCAND + c];
        const float4* wr = (const float4*)(Wenc + (size_t)di * D_);
        float acc = 0.f;
        #pragma unroll
        for (int j = 0; j < 4; j++) {
            const float4 q = wr[j * 64 + lane];
            const float4 p = ((const float4*)ln)[j * 64 + lane];
            acc += q.x * p.x + q.y * p.y + q.z * p.z + q.w * p.w;
        }
        #pragma unroll
        for (int off = 32; off > 0; off >>= 1) acc += __shfl_down(acc, off, 64);
        if (lane == 0) { dv[c] = acc; di_s[c] = di; }
    }
    __syncthreads();

    __shared__ float wv[TOPK];
    __shared__ int wi[TOPK];
    if (tid == 0) {
        unsigned int used = 0;
        for (int p = 0; p < TOPK; p++) {
            float bv = -FLT_MAX; int bc = -1;
            for (int c = 0; c < NCAND; c++) {
                if (used & (1u << c)) continue;
                const float cv = dv[c];
                if (cv > bv || (cv == bv && di_s[c] < ((bc >= 0) ? di_s[bc] : 0x7fffffff))) { bv = cv; bc = c; }
            }
            used |= 1u << bc;
            wv[p] = dv[bc]; wi[p] = di_s[bc];
        }
    }
    __syncthreads();
    if (tid < TOPK) {
        sel_val[(size_t)token * TOPK + tid] = wv[tid];
        sel_idx[(size_t)token * TOPK + tid] = wi[tid];
    }
}

// ---------------- K5: patch the 8 values + reconstruction (zeros already written) ----------------
__global__ __launch_bounds__(256) void patch_recon_kernel(const float* __restrict__ sel_val,
                                                          const int* __restrict__ sel_idx,
                                                          const float* __restrict__ Wdict,
                                                          float* __restrict__ sparse,
                                                          float* __restrict__ recon) {
    const int token = blockIdx.x;
    const int tid = threadIdx.x;
    __shared__ float v8[TOPK];
    __shared__ int i8[TOPK];
    if (tid < TOPK) {
        v8[tid] = sel_val[(size_t)token * TOPK + tid];
        i8[tid] = sel_idx[(size_t)token * TOPK + tid];
    }
    __syncthreads();

    float4 wr[TOPK];
    #pragma unroll
    for (int j = 0; j < TOPK; j++)
        wr[j] = ((const float4*)(Wdict + (size_t)i8[j] * D_))[tid];

    if (tid < TOPK)
        sparse[(size_t)token * DICT_ + i8[tid]] = v8[tid];

    float4 acc = {0.f, 0.f, 0.f, 0.f};
    #pragma unroll
    for (int j = 0; j < TOPK; j++) {
        const float c = v8[j];
        acc.x = fmaf(c, wr[j].x, acc.x);
        acc.y = fmaf(c, wr[j].y, acc.y);
        acc.z = fmaf(c, wr[j].z, acc.z);
        acc.w = fmaf(c, wr[j].w, acc.w);
    }
    ((float4*)(recon + (size_t)token * D_))[tid] = acc;
}

extern "C" void kernel_launch(void* const* d_in, const int* in_sizes, int n_in,
                              void* d_out, int out_size, void* d_ws, size_t ws_size,
                              hipStream_t stream) {
    const float* x = (const float*)d_in[0];
    const float* gamma = (const float*)d_in[1];
    const float* beta = (const float*)d_in[2];
    const float* Wenc = (const float*)d_in[3];
    const float* Wdict = (const float*)d_in[4];

    float* recon = (float*)d_out;
    float* sparse = (float*)d_out + (size_t)NTOK * D_;

    // scratch in d_ws (~178 MB)
    unsigned short* Lg = (unsigned short*)d_ws;                   // bf16 logits, 134 MB
    unsigned short* We = Lg + (size_t)NTOK * DICT_;               // bf16 W_enc, 33.5 MB
    unsigned short* Nb = We + (size_t)DICT_ * D_;                 // bf16 normed, 8 MB
    float* cbm = (float*)(Nb + (size_t)NTOK * D_);                // 4096*64 f32, 1 MB
    int* cand = (int*)(cbm + (size_t)NTOK * 64);                  // 4096*12 int
    float* sel_val = (float*)(cand + (size_t)NTOK * NCAND);       // 4096*8 f32
    int* sel_idx = (int*)(sel_val + (size_t)NTOK * TOPK);         // 4096*8 int

    ln_kernel<<<NTOK, 256, 0, stream>>>(x, gamma, beta, Nb);
    cvt_kernel<<<DICT_ * D_ / 4096, 256, 0, stream>>>(Wenc, We);

    dim3 gg(DICT_ / 256, NTOK / 256);
    gemm_kernel<<<gg, 512, 0, stream>>>(Nb, We, Lg, cbm, sparse);

    cand_kernel<<<NTOK, 256, 0, stream>>>(cbm, Lg, cand);

    refine_kernel<<<NTOK, 256, 0, stream>>>(x, gamma, beta, Wenc, cand,
                                            sel_val, sel_idx);

    patch_recon_kernel<<<NTOK, 256, 0, stream>>>(sel_val, sel_idx, Wdict,
                                                 sparse, recon);
}

// Round 14
// 276.941 us; speedup vs baseline: 1.1780x; 1.0951x over previous
//
#include <hip/hip_runtime.h>
#include <hip/hip_bf16.h>
#include <cfloat>

#define NTOK 4096
#define D_ 1024
#define DICT_ 16384
#define TOPK 8
#define NCAND 12
#define NBLKSEL 12
#define LN_EPS 1e-5f

typedef __attribute__((ext_vector_type(8))) short bf16x8;
typedef __attribute__((ext_vector_type(4))) float f32x4;
typedef __attribute__((ext_vector_type(8))) unsigned short us8;
typedef __attribute__((ext_vector_type(4))) unsigned short us4;

__device__ __forceinline__ unsigned short f2bf(float f) {
    unsigned int u = __float_as_uint(f);
    u += 0x7fffu + ((u >> 16) & 1u);   // RNE
    return (unsigned short)(u >> 16);
}
__device__ __forceinline__ float bf2f(unsigned short u) {
    return __uint_as_float(((unsigned int)u) << 16);
}

__device__ __forceinline__ void gl2lds16(const void* gsrc, void* ldsdst) {
    __builtin_amdgcn_global_load_lds(
        (const __attribute__((address_space(1))) unsigned int*)gsrc,
        (__attribute__((address_space(3))) unsigned int*)ldsdst, 16, 0, 0);
}

// ---------------- K1: fused LayerNorm (blocks 0..4095) + W_enc cvt (blocks 4096..20479) ----------------
__global__ __launch_bounds__(256) void prep_kernel(const float* __restrict__ x,
                                                   const float* __restrict__ gamma,
                                                   const float* __restrict__ beta,
                                                   unsigned short* __restrict__ nb,
                                                   const float* __restrict__ W,
                                                   unsigned short* __restrict__ Wb) {
    const int tid = threadIdx.x;
    if (blockIdx.x >= NTOK) {
        // cvt role: 4096 fp32 -> bf16 per block
        const size_t base = (size_t)(blockIdx.x - NTOK) * 1024;
        #pragma unroll
        for (int j = 0; j < 4; j++) {
            size_t i = base + j * 256 + tid;
            float4 f = ((const float4*)W)[i];
            us4 o;
            o.x = f2bf(f.x); o.y = f2bf(f.y); o.z = f2bf(f.z); o.w = f2bf(f.w);
            ((us4*)Wb)[i] = o;
        }
        return;
    }
    const int t = blockIdx.x;
    const float4 v = ((const float4*)(x + (size_t)t * D_))[tid];

    float s = v.x + v.y + v.z + v.w;
    #pragma unroll
    for (int off = 32; off > 0; off >>= 1) s += __shfl_down(s, off, 64);
    __shared__ float red[4];
    int wid = tid >> 6, lane = tid & 63;
    if (lane == 0) red[wid] = s;
    __syncthreads();
    float mu = (red[0] + red[1] + red[2] + red[3]) * (1.0f / D_);
    __syncthreads();

    float dx = v.x - mu, dy = v.y - mu, dz = v.z - mu, dw = v.w - mu;
    float ss = dx * dx + dy * dy + dz * dz + dw * dw;
    #pragma unroll
    for (int off = 32; off > 0; off >>= 1) ss += __shfl_down(ss, off, 64);
    if (lane == 0) red[wid] = ss;
    __syncthreads();
    float var = (red[0] + red[1] + red[2] + red[3]) * (1.0f / D_);
    float rs = rsqrtf(var + LN_EPS);

    const float4 g = ((const float4*)gamma)[tid];
    const float4 b = ((const float4*)beta)[tid];
    us4 o;
    o.x = f2bf(dx * rs * g.x + b.x);
    o.y = f2bf(dy * rs * g.y + b.y);
    o.z = f2bf(dz * rs * g.z + b.z);
    o.w = f2bf(dw * rs * g.w + b.w);
    ((us4*)(nb + (size_t)t * D_))[tid] = o;
}

// ---------------- K2: 256x256 bf16 MFMA GEMM + blockmax + streamed zero-fill ----------------
// (unchanged from R13)
__global__ __launch_bounds__(512, 1) void gemm_kernel(const unsigned short* __restrict__ A,
                                                      const unsigned short* __restrict__ B,
                                                      unsigned short* __restrict__ L,
                                                      float* __restrict__ cbm,
                                                      float* __restrict__ Z) {
    __shared__ unsigned short lds[2][2][256][64];
    const int tid = threadIdx.x;
    const int lane = tid & 63;
    const int w = tid >> 6;
    const int wm = w >> 2, wn = w & 3;
    const int col0 = blockIdx.x * 256;   // dict cols
    const int row0 = blockIdx.y * 256;   // token rows

    f32x4 acc[8][4] = {};

    auto stage = [&](int b, int mat, const unsigned short* __restrict__ G,
                     int rbase, int k0, int h) {
        unsigned short* plane = &lds[b][mat][0][0];
        #pragma unroll
        for (int i = 0; i < 2; i++) {
            const int cb = h * 1024 + i * 512 + w * 64;   // wave-uniform chunk base
            const int c = cb + lane;
            const int r = c >> 3, sl = c & 7, g = sl ^ (r & 7);
            gl2lds16(G + (size_t)(rbase + r) * 1024 + k0 + g * 8, plane + (size_t)cb * 8);
        }
    };

    // prologue: stage tile 0 into buf 0
    stage(0, 0, A, row0, 0, 0);
    stage(0, 0, A, row0, 0, 1);
    stage(0, 1, B, col0, 0, 0);
    stage(0, 1, B, col0, 0, 1);

    const int arow = wm * 128 + (lane & 15);
    const int brow = wn * 64 + (lane & 15);
    const int kg = lane >> 4;

    for (int t = 0; t < 16; t++) {
        const int cur = t & 1, nxt = cur ^ 1;
        const int kn = ((t + 1) & 15) * 64;   // wrap-around keeps loop uniform

        // ---- phase 0: issue next A halves; wait tile t (leave 4 in flight); kk0, n={0,1}
        stage(nxt, 0, A, row0, kn, 0);
        stage(nxt, 0, A, row0, kn, 1);
        asm volatile("s_waitcnt vmcnt(4)" ::: "memory");
        __builtin_amdgcn_s_barrier();
        __builtin_amdgcn_sched_barrier(0);
        asm volatile("" ::: "memory");

        bf16x8 af[8];
        #pragma unroll
        for (int m = 0; m < 8; m++) {
            const int r = arow + m * 16;
            af[m] = *(const bf16x8*)&lds[cur][0][r][(kg ^ (r & 7)) * 8];
        }
        bf16x8 b0, b1;
        { const int r = brow;      b0 = *(const bf16x8*)&lds[cur][1][r][(kg ^ (r & 7)) * 8]; }
        { const int r = brow + 16; b1 = *(const bf16x8*)&lds[cur][1][r][(kg ^ (r & 7)) * 8]; }
        __builtin_amdgcn_s_setprio(1);
        #pragma unroll
        for (int m = 0; m < 8; m++) {
            acc[m][0] = __builtin_amdgcn_mfma_f32_16x16x32_bf16(af[m], b0, acc[m][0], 0, 0, 0);
            acc[m][1] = __builtin_amdgcn_mfma_f32_16x16x32_bf16(af[m], b1, acc[m][1], 0, 0, 0);
        }
        __builtin_amdgcn_s_setprio(0);

        // ---- phase 1: issue next B halves; kk0, n={2,3}
        stage(nxt, 1, B, col0, kn, 0);
        stage(nxt, 1, B, col0, kn, 1);
        { const int r = brow + 32; b0 = *(const bf16x8*)&lds[cur][1][r][(kg ^ (r & 7)) * 8]; }
        { const int r = brow + 48; b1 = *(const bf16x8*)&lds[cur][1][r][(kg ^ (r & 7)) * 8]; }
        __builtin_amdgcn_s_setprio(1);
        #pragma unroll
        for (int m = 0; m < 8; m++) {
            acc[m][2] = __builtin_amdgcn_mfma_f32_16x16x32_bf16(af[m], b0, acc[m][2], 0, 0, 0);
            acc[m][3] = __builtin_amdgcn_mfma_f32_16x16x32_bf16(af[m], b1, acc[m][3], 0, 0, 0);
        }
        __builtin_amdgcn_s_setprio(0);

        // ---- phase 2: kk1, n={0,1}
        #pragma unroll
        for (int m = 0; m < 8; m++) {
            const int r = arow + m * 16;
            af[m] = *(const bf16x8*)&lds[cur][0][r][((4 + kg) ^ (r & 7)) * 8];
        }
        { const int r = brow;      b0 = *(const bf16x8*)&lds[cur][1][r][((4 + kg) ^ (r & 7)) * 8]; }
        { const int r = brow + 16; b1 = *(const bf16x8*)&lds[cur][1][r][((4 + kg) ^ (r & 7)) * 8]; }
        __builtin_amdgcn_s_setprio(1);
        #pragma unroll
        for (int m = 0; m < 8; m++) {
            acc[m][0] = __builtin_amdgcn_mfma_f32_16x16x32_bf16(af[m], b0, acc[m][0], 0, 0, 0);
            acc[m][1] = __builtin_amdgcn_mfma_f32_16x16x32_bf16(af[m], b1, acc[m][1], 0, 0, 0);
        }
        __builtin_amdgcn_s_setprio(0);

        // ---- phase 3: kk1, n={2,3}
        { const int r = brow + 32; b0 = *(const bf16x8*)&lds[cur][1][r][((4 + kg) ^ (r & 7)) * 8]; }
        { const int r = brow + 48; b1 = *(const bf16x8*)&lds[cur][1][r][((4 + kg) ^ (r & 7)) * 8]; }
        __builtin_amdgcn_s_setprio(1);
        #pragma unroll
        for (int m = 0; m < 8; m++) {
            acc[m][2] = __builtin_amdgcn_mfma_f32_16x16x32_bf16(af[m], b0, acc[m][2], 0, 0, 0);
            acc[m][3] = __builtin_amdgcn_mfma_f32_16x16x32_bf16(af[m], b1, acc[m][3], 0, 0, 0);
        }
        __builtin_amdgcn_s_setprio(0);

        __builtin_amdgcn_s_barrier();
        __builtin_amdgcn_sched_barrier(0);
        asm volatile("" ::: "memory");
    }

    // ---- blockmax: per-(m,r) row max over this thread's 16 cols, fully static ----
    float rmax[8][4];
    #pragma unroll
    for (int m = 0; m < 8; m++)
        #pragma unroll
        for (int r = 0; r < 4; r++)
            rmax[m][r] = fmaxf(fmaxf(acc[m][0][r], acc[m][1][r]),
                               fmaxf(acc[m][2][r], acc[m][3][r]));
    #pragma unroll
    for (int m = 0; m < 8; m++)
        #pragma unroll
        for (int r = 0; r < 4; r++) {
            float v = rmax[m][r];
            v = fmaxf(v, __shfl_xor(v, 1, 64));
            v = fmaxf(v, __shfl_xor(v, 2, 64));
            v = fmaxf(v, __shfl_xor(v, 4, 64));
            v = fmaxf(v, __shfl_xor(v, 8, 64));
            rmax[m][r] = v;
        }

    // drain in-flight wrap-around staging DMA, then reuse LDS for cross-wave max
    asm volatile("s_waitcnt vmcnt(0)" ::: "memory");
    __builtin_amdgcn_s_barrier();
    __builtin_amdgcn_sched_barrier(0);

    float* bm = (float*)&lds[0][0][0][0];   // [4 wn][256 rows] = 4 KB
    if ((lane & 15) == 0) {
        const int q = lane >> 4;
        #pragma unroll
        for (int m = 0; m < 8; m++)
            #pragma unroll
            for (int r = 0; r < 4; r++)
                bm[wn * 256 + wm * 128 + m * 16 + q * 4 + r] = rmax[m][r];
    }
    __syncthreads();
    if (tid < 256) {
        const float b0 = fmaxf(fmaxf(bm[tid], bm[256 + tid]),
                               fmaxf(bm[512 + tid], bm[768 + tid]));
        cbm[(size_t)(row0 + tid) * 64 + blockIdx.x] = b0;
    }

    // logits write: C/D layout col=lane&15, row=(lane>>4)*4+reg
    #pragma unroll
    for (int m = 0; m < 8; m++) {
        const int rb = row0 + wm * 128 + m * 16 + (lane >> 4) * 4;
        #pragma unroll
        for (int n = 0; n < 4; n++) {
            const int col = col0 + wn * 64 + n * 16 + (lane & 15);
            #pragma unroll
            for (int r = 0; r < 4; r++)
                L[(size_t)(rb + r) * DICT_ + col] = f2bf(acc[m][n][r]);
        }
    }

    // ---- streamed zero-fill of this block's 256 KB slice of the sparse output ----
    {
        const f32x4 z = {0.f, 0.f, 0.f, 0.f};
        f32x4* zrow = (f32x4*)(Z + (size_t)(blockIdx.y * 64 + blockIdx.x) * 65536);
        #pragma unroll
        for (int i = 0; i < 32; i++)
            __builtin_nontemporal_store(z, zrow + i * 512 + tid);
    }
}

// ---------------- K3: fused select: blocks -> candidates -> exact refine -> patch + recon ----------------
__global__ __launch_bounds__(256) void select_kernel(const float* __restrict__ cbm,
                                                     const unsigned short* __restrict__ L,
                                                     const float* __restrict__ x,
                                                     const float* __restrict__ gamma,
                                                     const float* __restrict__ beta,
                                                     const float* __restrict__ Wenc,
                                                     const float* __restrict__ Wdict,
                                                     float* __restrict__ sparse,
                                                     float* __restrict__ recon) {
    const int token = blockIdx.x;
    const int tid = threadIdx.x;
    const int lane = tid & 63;
    const int wv4 = tid >> 6;

    __shared__ float red[4];
    __shared__ float ln[D_];
    __shared__ int blksel[NBLKSEL];

    // ---- LayerNorm (fp32, matches reference) ----
    const float4 v = ((const float4*)(x + (size_t)token * D_))[tid];
    float s = v.x + v.y + v.z + v.w;
    #pragma unroll
    for (int off = 32; off > 0; off >>= 1) s += __shfl_down(s, off, 64);
    if (lane == 0) red[wv4] = s;
    __syncthreads();
    float mu = (red[0] + red[1] + red[2] + red[3]) * (1.0f / D_);
    __syncthreads();
    float dx = v.x - mu, dy = v.y - mu, dz = v.z - mu, dw = v.w - mu;
    float ss = dx * dx + dy * dy + dz * dz + dw * dw;
    #pragma unroll
    for (int off = 32; off > 0; off >>= 1) ss += __shfl_down(ss, off, 64);
    if (lane == 0) red[wv4] = ss;
    __syncthreads();
    float var = (red[0] + red[1] + red[2] + red[3]) * (1.0f / D_);
    float rs = rsqrtf(var + LN_EPS);
    const float4 g = ((const float4*)gamma)[tid];
    const float4 b = ((const float4*)beta)[tid];
    float4 o;
    o.x = dx * rs * g.x + b.x;
    o.y = dy * rs * g.y + b.y;
    o.z = dz * rs * g.z + b.z;
    o.w = dw * rs * g.w + b.w;
    ((float4*)ln)[tid] = o;

    // ---- top-12 blocks by blockmax (deterministic: k-th value lies in top-k blocks) ----
    if (tid < 64) {
        float bv0 = cbm[(size_t)token * 64 + tid];
        for (int round = 0; round < NBLKSEL; round++) {
            float bv = bv0; int bi = tid;
            #pragma unroll
            for (int off = 32; off > 0; off >>= 1) {
                const float ov = __shfl_xor(bv, off, 64);
                const int oi = __shfl_xor(bi, off, 64);
                if (ov > bv || (ov == bv && oi < bi)) { bv = ov; bi = oi; }
            }
            if (tid == 0) blksel[round] = bi;
            if (tid == bi) bv0 = -FLT_MAX;
        }
    }
    __syncthreads();

    // ---- scan 12 selected blocks (3072 cols) -> per-thread top-4 ----
    float v4[4]; int id4[4];
    #pragma unroll
    for (int j = 0; j < 4; j++) { v4[j] = -FLT_MAX; id4[j] = -1; }
    // 12 blocks x 32 groups-of-8: thread handles group (tid&31) of block blksel[tid>>5] (pass0: 8 blocks)
    #pragma unroll
    for (int pass = 0; pass < 2; pass++) {
        if (pass == 1 && tid >= 128) break;
        const int b = blksel[pass * 8 + (tid >> 5)];
        const int colbase = b * 256 + (tid & 31) * 8;
        const us8 u = *(const us8*)&L[(size_t)token * DICT_ + colbase];
        #pragma unroll
        for (int e = 0; e < 8; e++) {
            const float f = bf2f(u[e]);
            if (f > v4[3]) {
                v4[3] = f; id4[3] = colbase + e;
                #pragma unroll
                for (int q = 3; q > 0; q--) {
                    if (v4[q] > v4[q - 1]) {
                        float tf = v4[q]; v4[q] = v4[q - 1]; v4[q - 1] = tf;
                        int ti = id4[q]; id4[q] = id4[q - 1]; id4[q - 1] = ti;
                    }
                }
            }
        }
    }
    // pass covers blocks 0..15 slots but only 12 valid: guard pass1 upper half
    // (pass1 uses blksel[8 + (tid>>5)], tid<128 -> indices 8..11: exactly blocks 8..11)

    __shared__ float hv[256];
    __shared__ int hi[256];
    __shared__ int cnd[NCAND];
    __shared__ int wt;
    hv[tid] = v4[0];
    hi[tid] = id4[0];
    int myp = 0;

    for (int round = 0; round < NCAND; round++) {
        __syncthreads();
        if (tid < 64) {
            float bv = hv[tid]; int bt = tid;
            #pragma unroll
            for (int q = 1; q < 4; q++) {
                const int t2 = tid + q * 64;
                const float v2 = hv[t2];
                if (v2 > bv || (v2 == bv && t2 < bt)) { bv = v2; bt = t2; }
            }
            #pragma unroll
            for (int off = 32; off > 0; off >>= 1) {
                const float ov = __shfl_down(bv, off, 64);
                const int ot = __shfl_down(bt, off, 64);
                if (ov > bv || (ov == bv && ot < bt)) { bv = ov; bt = ot; }
            }
            if (tid == 0) wt = bt;
        }
        __syncthreads();
        if (tid == wt) {
            cnd[round] = hi[tid];
            myp++;
            if (myp < 4) { hv[tid] = v4[myp]; hi[tid] = id4[myp]; }
            else { hv[tid] = -FLT_MAX; hi[tid] = -1; }
        }
    }
    __syncthreads();

    // ---- exact fp32 refine of the 12 candidates ----
    __shared__ float dv[NCAND];
    __shared__ int di_s[NCAND];
    for (int c = wv4; c < NCAND; c += 4) {
        const int di = cnd[c];
        const float4* wr = (const float4*)(Wenc + (size_t)di * D_);
        float acc = 0.f;
        #pragma unroll
        for (int j = 0; j < 4; j++) {
            const float4 q = wr[j * 64 + lane];
            const float4 p = ((const float4*)ln)[j * 64 + lane];
            acc += q.x * p.x + q.y * p.y + q.z * p.z + q.w * p.w;
        }
        #pragma unroll
        for (int off = 32; off > 0; off >>= 1) acc += __shfl_down(acc, off, 64);
        if (lane == 0) { dv[c] = acc; di_s[c] = di; }
    }
    __syncthreads();

    __shared__ float wvv[TOPK];
    __shared__ int wii[TOPK];
    if (tid == 0) {
        unsigned int used = 0;
        for (int p = 0; p < TOPK; p++) {
            float bv = -FLT_MAX; int bc = -1;
            for (int c = 0; c < NCAND; c++) {
                if (used & (1u << c)) continue;
                const float cv = dv[c];
                if (cv > bv || (cv == bv && di_s[c] < ((bc >= 0) ? di_s[bc] : 0x7fffffff))) { bv = cv; bc = c; }
            }
            used |= 1u << bc;
            wvv[p] = dv[bc]; wii[p] = di_s[bc];
        }
    }
    __syncthreads();

    // ---- patch the 8 values (zeros already streamed by gemm) + reconstruction ----
    float4 wr8[TOPK];
    #pragma unroll
    for (int j = 0; j < TOPK; j++)
        wr8[j] = ((const float4*)(Wdict + (size_t)wii[j] * D_))[tid];

    if (tid < TOPK)
        sparse[(size_t)token * DICT_ + wii[tid]] = wvv[tid];

    float4 acc = {0.f, 0.f, 0.f, 0.f};
    #pragma unroll
    for (int j = 0; j < TOPK; j++) {
        const float c = wvv[j];
        acc.x = fmaf(c, wr8[j].x, acc.x);
        acc.y = fmaf(c, wr8[j].y, acc.y);
        acc.z = fmaf(c, wr8[j].z, acc.z);
        acc.w = fmaf(c, wr8[j].w, acc.w);
    }
    ((float4*)(recon + (size_t)token * D_))[tid] = acc;
}

extern "C" void kernel_launch(void* const* d_in, const int* in_sizes, int n_in,
                              void* d_out, int out_size, void* d_ws, size_t ws_size,
                              hipStream_t stream) {
    const float* x = (const float*)d_in[0];
    const float* gamma = (const float*)d_in[1];
    const float* beta = (const float*)d_in[2];
    const float* Wenc = (const float*)d_in[3];
    const float* Wdict = (const float*)d_in[4];

    float* recon = (float*)d_out;
    float* sparse = (float*)d_out + (size_t)NTOK * D_;

    // scratch in d_ws (~178 MB)
    unsigned short* Lg = (unsigned short*)d_ws;                   // bf16 logits, 134 MB
    unsigned short* We = Lg + (size_t)NTOK * DICT_;               // bf16 W_enc, 33.5 MB
    unsigned short* Nb = We + (size_t)DICT_ * D_;                 // bf16 normed, 8 MB
    float* cbm = (float*)(Nb + (size_t)NTOK * D_);                // 4096*64 f32, 1 MB

    prep_kernel<<<NTOK + DICT_ * D_ / 4096, 256, 0, stream>>>(x, gamma, beta, Nb, Wenc, We);

    dim3 gg(DICT_ / 256, NTOK / 256);
    gemm_kernel<<<gg, 512, 0, stream>>>(Nb, We, Lg, cbm, sparse);

    select_kernel<<<NTOK, 256, 0, stream>>>(cbm, Lg, x, gamma, beta, Wenc, Wdict,
                                            sparse, recon);
}